// Round 6
// baseline (317.356 us; speedup 1.0000x reference)
//
#include <hip/hip_runtime.h>
#include <math.h>

#define NN 4096
#define EE 131072
#define IN_DIM 512
#define HID 256
#define OUT_DIM 64
#define ECAP 128

typedef __attribute__((ext_vector_type(8))) short bf8_t;
typedef __attribute__((ext_vector_type(4))) float f4_t;
typedef __attribute__((ext_vector_type(8))) unsigned short us8_t;

#define GAS __attribute__((address_space(1)))
#define LAS __attribute__((address_space(3)))

// ---------------- bf16 helpers (RNE) ----------------
__device__ __forceinline__ unsigned short f2bf(float v){
  union { float f; unsigned u; } x; x.f = v;
  unsigned r = x.u + 0x7fffu + ((x.u >> 16) & 1u);
  return (unsigned short)(r >> 16);
}
__device__ __forceinline__ float bf2f(unsigned short h){
  union { float f; unsigned u; } x; x.u = ((unsigned)h) << 16;
  return x.f;
}

__device__ __forceinline__ float waveReduceSum(float v){
#pragma unroll
  for (int off = 32; off > 0; off >>= 1) v += __shfl_down(v, off);
  return v;
}

// ---------------- graph build: bitmask + ELL ----------------
__global__ void k_build_bits(const int* __restrict__ ei, unsigned* __restrict__ bits){
  int e = blockIdx.x * blockDim.x + threadIdx.x;
  if (e < EE){
    int r = ei[e], c = ei[EE + e];
    atomicOr(&bits[r * 128 + (c >> 5)], 1u << (c & 31));
  }
}

__global__ __launch_bounds__(128) void k_ell(const unsigned* __restrict__ bits,
                                             int* __restrict__ ell, int* __restrict__ cnt,
                                             float* __restrict__ dinv){
  int r = blockIdx.x, t = threadIdx.x;
  unsigned w = bits[r * 128 + t];
  int c = __popc(w);
  __shared__ int sc[128];
  sc[t] = c; __syncthreads();
  for (int off = 1; off < 128; off <<= 1){
    int a = sc[t], b = (t >= off) ? sc[t - off] : 0;
    __syncthreads(); sc[t] = a + b; __syncthreads();
  }
  int total = sc[127];
  int pos = sc[t] - c;
  int base = r * ECAP;
  while (w){
    int b = __ffs(w) - 1; w &= w - 1;
    if (pos < ECAP) ell[base + pos] = t * 32 + b;
    pos++;
  }
  if (t == 0){
    cnt[r] = (total < ECAP) ? total : ECAP;
    dinv[r] = 1.0f / sqrtf((float)total + 2.0f);
  }
}

// ---------------- fused SpMM (ELL, values==1) + GCN epilogue (+ optional score) ----------------
template<int NCOLS, int RELU, int SC>
__global__ __launch_bounds__(256) void k_spmm_ell(
    const int* __restrict__ ell, const int* __restrict__ cnt,
    const float* __restrict__ Zs, const float* __restrict__ dinv,
    const float* __restrict__ bias, float* __restrict__ out,
    const float* __restrict__ scw, float* __restrict__ score)
{
  int r = blockIdx.x;
  __shared__ int s_idx[ECAP];
  __shared__ int s_n;
  __shared__ float sh[4 * NCOLS];
  __shared__ float sd[4], sq[4];
  if (threadIdx.x == 0) s_n = cnt[r];
  for (int i = threadIdx.x; i < ECAP; i += 256) s_idx[i] = ell[r * ECAP + i];
  __syncthreads();
  int n = s_n; if (n > ECAP) n = ECAP;
  int wv = threadIdx.x >> 6, lane = threadIdx.x & 63;
  if (NCOLS == 256){
    f4_t acc = (f4_t){0.f, 0.f, 0.f, 0.f};
    for (int e = wv; e < n; e += 4){
      const f4_t* row = (const f4_t*)(Zs + (size_t)s_idx[e] * 256);
      acc += row[lane];
    }
    ((f4_t*)(sh + wv * 256))[lane] = acc;
  } else {
    float acc = 0.f;
    for (int e = wv; e < n; e += 4)
      acc += Zs[(size_t)s_idx[e] * 64 + lane];
    sh[wv * 64 + lane] = acc;
  }
  __syncthreads();
  int t = threadIdx.x;
  float o = 0.f;
  if (t < NCOLS){
    float y = sh[t] + sh[NCOLS + t] + sh[2 * NCOLS + t] + sh[3 * NCOLS + t];
    float z = Zs[(size_t)r * NCOLS + t];
    o = dinv[r] * (y + 2.0f * z) + bias[t];
    if (RELU) o = fmaxf(o, 0.f);
    out[(size_t)r * NCOLS + t] = o;
  }
  if (SC){
    float w = scw[t];
    float d = waveReduceSum(o * w);
    float q = waveReduceSum(w * w);
    if (!lane){ sd[wv] = d; sq[wv] = q; }
    __syncthreads();
    if (!t) score[r] = tanhf((sd[0] + sd[1] + sd[2] + sd[3]) / sqrtf(sq[0] + sq[1] + sq[2] + sq[3]));
  }
}

// ---------------- pool-1 squaring (u8 Rb) ----------------
__global__ __launch_bounds__(256) void k_build_Rb(const int* __restrict__ ell, const int* __restrict__ cnt,
                                                  const int* __restrict__ invsel,
                                                  unsigned char* __restrict__ Rb){
  int k = blockIdx.x;
  __shared__ unsigned char row[2048];
  for (int i = threadIdx.x; i < 512; i += 256) ((int*)row)[i] = 0;
  __syncthreads();
  int n = cnt[k];
  for (int e = threadIdx.x; e < n; e += 256){
    int s = invsel[ell[k * ECAP + e]];
    if (s >= 0) row[s] = 1;
  }
  __syncthreads();
  if (threadIdx.x == 0){
    int sk = invsel[k];
    if (sk >= 0) row[sk] += 1;
  }
  __syncthreads();
  *(uint2*)(Rb + (size_t)k * 2048 + threadIdx.x * 8) = *(uint2*)(row + threadIdx.x * 8);
}

__global__ __launch_bounds__(256) void k_sq1(const int* __restrict__ ell, const int* __restrict__ cnt,
                                             const int* __restrict__ perm,
                                             const unsigned char* __restrict__ Rb,
                                             unsigned short* __restrict__ A1h,
                                             float* __restrict__ dinv1){
  int r = blockIdx.x;
  int pr = perm[r];
  __shared__ int s_idx[ECAP];
  __shared__ int s_n;
  __shared__ float sred[4];
  if (threadIdx.x == 0) s_n = cnt[pr];
  for (int i = threadIdx.x; i < ECAP; i += 256) s_idx[i] = ell[pr * ECAP + i];
  __syncthreads();
  int n = s_n; if (n > ECAP) n = ECAP;
  int colb = threadIdx.x * 8;
  uint2 acc = *(const uint2*)(Rb + (size_t)pr * 2048 + colb);
  for (int e = 0; e < n; ++e){
    uint2 v = *(const uint2*)(Rb + (size_t)s_idx[e] * 2048 + colb);
    acc.x += v.x; acc.y += v.y;   // bytewise, no carries (values <=130)
  }
  float fs = 0.f;
  us8_t o;
#pragma unroll
  for (int j = 0; j < 8; ++j){
    unsigned byte = ((j < 4 ? acc.x : acc.y) >> (8 * (j & 3))) & 0xFFu;
    if (colb + j == r) byte = 0;
    float f = (float)byte;
    fs += f;
    o[j] = f2bf(f);
  }
  *(us8_t*)(A1h + (size_t)r * 2048 + colb) = o;
  fs = waveReduceSum(fs);
  int lane = threadIdx.x & 63, wd = threadIdx.x >> 6;
  if (!lane) sred[wd] = fs;
  __syncthreads();
  if (!threadIdx.x)
    dinv1[r] = 1.0f / sqrtf(sred[0] + sred[1] + sred[2] + sred[3] + 2.0f);
}

// ---------------- bf16 transpose (h [+l]) ----------------
template<int TWO>
__global__ __launch_bounds__(256) void k_tr_b(const unsigned short* __restrict__ Sh,
                                              const unsigned short* __restrict__ Sl,
                                              unsigned short* __restrict__ Dh,
                                              unsigned short* __restrict__ Dl, int R, int C){
  __shared__ unsigned short th[32][33];
  __shared__ unsigned short tl[TWO ? 32 : 1][TWO ? 33 : 1];
  int bx = blockIdx.x * 32, by = blockIdx.y * 32;
  int tx = threadIdx.x & 31, ty = threadIdx.x >> 5;
#pragma unroll
  for (int i = 0; i < 4; ++i){
    th[ty + i * 8][tx] = Sh[(size_t)(by + ty + i * 8) * C + bx + tx];
    if (TWO) tl[ty + i * 8][tx] = Sl[(size_t)(by + ty + i * 8) * C + bx + tx];
  }
  __syncthreads();
#pragma unroll
  for (int i = 0; i < 4; ++i){
    size_t o = (size_t)(bx + ty + i * 8) * R + by + tx;
    Dh[o] = th[tx][ty + i * 8];
    if (TWO) Dl[o] = tl[tx][ty + i * 8];
  }
}

template<int SRCL>
__global__ void k_dinv_bf(const unsigned short* __restrict__ Ah,
                          const unsigned short* __restrict__ Al,
                          float* __restrict__ dinv, int n){
  int row = blockIdx.x;
  float s = 0.f;
  for (int j = threadIdx.x; j < n; j += 256){
    float v = bf2f(Ah[(size_t)row * n + j]);
    if (SRCL) v += bf2f(Al[(size_t)row * n + j]);
    s += v;
  }
  s = waveReduceSum(s);
  __shared__ float sh[4];
  int lane = threadIdx.x & 63, wid = threadIdx.x >> 6;
  if (lane == 0) sh[wid] = s;
  __syncthreads();
  if (threadIdx.x == 0){
    float d = sh[0] + sh[1] + sh[2] + sh[3] + 2.0f;
    dinv[row] = (d > 0.f) ? (1.0f / sqrtf(d)) : 0.0f;
  }
}

// ---------------- MFMA GEMM: global_load_lds double-buffered + fused epilogues ----------------
// C(MxN) = (Ah[+Al]) @ (Bh[+Bl]); A [M][K] bf16 row-major, B as Bt [N][K] bf16.
// EPI 1: split acc -> Ch,Cl (flag: zero diagonal first)
// EPI 2: Cf = dinv[row]*acc
// EPI 3: Cf = act(dinv[row]*(acc + 2*Zs) + bias), flag = relu
// EPI 4: sv = dinv[row]*acc; Cf = sv; Ch/Cl[col*M+row] = split(sv)  (transposed split)
template<int HAS_AL, int HAS_BL, int HAS_LL, int EPI>
__global__ __launch_bounds__(256) void k_mm(
    const unsigned short* __restrict__ Ah, const unsigned short* __restrict__ Al,
    const unsigned short* __restrict__ Bh, const unsigned short* __restrict__ Bl,
    int M, int N, int K,
    float* __restrict__ Cf, unsigned short* __restrict__ Ch, unsigned short* __restrict__ Cl,
    const float* __restrict__ dinv, const float* __restrict__ Zs,
    const float* __restrict__ bias, int flag)
{
  constexpr int NARR = 2 + HAS_AL + HAS_BL;
  constexpr int BUF = NARR * 8192;
  __shared__ int4 ldsq[NARR * 512 * 2];
  char* ldsc = (char*)ldsq;

  const int tid = threadIdx.x, lane = tid & 63, wid = tid >> 6;
  const int wm = wid >> 1, wn = wid & 1;
  const int bm = blockIdx.y << 6, bn = blockIdx.x << 6;
  const int l15 = lane & 15, l4 = lane >> 4;

  f4_t acc[2][2];
#pragma unroll
  for (int i = 0; i < 2; ++i)
#pragma unroll
    for (int j = 0; j < 2; ++j) acc[i][j] = (f4_t){0.f, 0.f, 0.f, 0.f};

  const size_t rb = (size_t)K * 2;
  const char* pAh = (const char*)Ah + (size_t)bm * rb;
  const char* pAl = HAS_AL ? (const char*)Al + (size_t)bm * rb : nullptr;
  const char* pBh = (const char*)Bh + (size_t)bn * rb;
  const char* pBl = HAS_BL ? (const char*)Bl + (size_t)bn * rb : nullptr;

  auto stage = [&](int t, int b2){
    char* ldsb = ldsc + b2 * BUF;
    const size_t kb = (size_t)t * 128;
#pragma unroll
    for (int it = 0; it < 2; ++it){
      const int idx = tid + (it << 8);
      const int row = idx >> 3;
      const int kc = ((idx & 7) << 4) ^ ((row & 7) << 4);  // pre-swizzled source col
      const size_t go = (size_t)row * rb + kb + kc;
      const int lo = idx * 16;                             // linear LDS dest
      __builtin_amdgcn_global_load_lds((const GAS void*)(pAh + go), (LAS void*)(ldsb + lo), 16, 0, 0);
      __builtin_amdgcn_global_load_lds((const GAS void*)(pBh + go), (LAS void*)(ldsb + 8192 + lo), 16, 0, 0);
      if (HAS_AL)
        __builtin_amdgcn_global_load_lds((const GAS void*)(pAl + go), (LAS void*)(ldsb + 16384 + lo), 16, 0, 0);
      if (HAS_BL)
        __builtin_amdgcn_global_load_lds((const GAS void*)(pBl + go), (LAS void*)(ldsb + (2 + HAS_AL) * 8192 + lo), 16, 0, 0);
    }
  };

  const int T = K >> 6;
  stage(0, 0);
  int b = 0;
  for (int t = 0; t < T; ++t){
    if (t + 1 < T){
      stage(t + 1, b ^ 1);
      if constexpr (NARR == 2) asm volatile("s_waitcnt vmcnt(4)" ::: "memory");
      else if constexpr (NARR == 3) asm volatile("s_waitcnt vmcnt(6)" ::: "memory");
      else asm volatile("s_waitcnt vmcnt(8)" ::: "memory");
    } else {
      asm volatile("s_waitcnt vmcnt(0)" ::: "memory");
    }
    __syncthreads();
    const char* ldsb = ldsc + b * BUF;
#pragma unroll
    for (int ks = 0; ks < 2; ++ks){
      bf8_t aH[2], aL[2], bH[2], bL[2];
#pragma unroll
      for (int f = 0; f < 2; ++f){
        int ar = wm * 32 + f * 16 + l15;
        int aoff = ar * 128 + (((ks * 64) + (l4 << 4)) ^ ((ar & 7) << 4));
        aH[f] = *(const bf8_t*)(ldsb + aoff);
        if (HAS_AL) aL[f] = *(const bf8_t*)(ldsb + 16384 + aoff);
        int br = wn * 32 + f * 16 + l15;
        int boff = br * 128 + (((ks * 64) + (l4 << 4)) ^ ((br & 7) << 4));
        bH[f] = *(const bf8_t*)(ldsb + 8192 + boff);
        if (HAS_BL) bL[f] = *(const bf8_t*)(ldsb + (2 + HAS_AL) * 8192 + boff);
      }
#pragma unroll
      for (int i = 0; i < 2; ++i)
#pragma unroll
        for (int j = 0; j < 2; ++j){
          acc[i][j] = __builtin_amdgcn_mfma_f32_16x16x32_bf16(aH[i], bH[j], acc[i][j], 0, 0, 0);
          if (HAS_BL) acc[i][j] = __builtin_amdgcn_mfma_f32_16x16x32_bf16(aH[i], bL[j], acc[i][j], 0, 0, 0);
          if (HAS_AL) acc[i][j] = __builtin_amdgcn_mfma_f32_16x16x32_bf16(aL[i], bH[j], acc[i][j], 0, 0, 0);
          if (HAS_LL) acc[i][j] = __builtin_amdgcn_mfma_f32_16x16x32_bf16(aL[i], bL[j], acc[i][j], 0, 0, 0);
        }
    }
    __syncthreads();
    b ^= 1;
  }

#pragma unroll
  for (int i = 0; i < 2; ++i)
#pragma unroll
    for (int j = 0; j < 2; ++j)
#pragma unroll
      for (int r = 0; r < 4; ++r){
        int grow = bm + wm * 32 + i * 16 + l4 * 4 + r;
        int gcol = bn + wn * 32 + j * 16 + l15;
        float v = acc[i][j][r];
        size_t o = (size_t)grow * N + gcol;
        if (EPI == 1){
          if (flag && grow == gcol) v = 0.f;
          unsigned short h = f2bf(v);
          Ch[o] = h; Cl[o] = f2bf(v - bf2f(h));
        } else if (EPI == 2){
          Cf[o] = dinv[grow] * v;
        } else if (EPI == 3){
          float out = dinv[grow] * (v + 2.0f * Zs[o]) + bias[gcol];
          if (flag) out = fmaxf(out, 0.f);
          Cf[o] = out;
        } else { // EPI == 4
          float sv = dinv[grow] * v;
          Cf[o] = sv;
          unsigned short h = f2bf(sv);
          size_t ot = (size_t)gcol * M + grow;
          Ch[ot] = h; Cl[ot] = f2bf(sv - bf2f(h));
        }
      }
}

// ---------------- elementwise helpers ----------------
__global__ void k_split(const float* __restrict__ X, unsigned short* __restrict__ H,
                        unsigned short* __restrict__ L, int n){
  int i = blockIdx.x * 256 + threadIdx.x;
  if (i < n){
    float v = X[i];
    unsigned short h = f2bf(v);
    H[i] = h; L[i] = f2bf(v - bf2f(h));
  }
}

__global__ __launch_bounds__(256) void k_tsplit(const float* __restrict__ X, int R, int C,
                                                unsigned short* __restrict__ Th,
                                                unsigned short* __restrict__ Tl){
  __shared__ float t[32][33];
  int bx = blockIdx.x * 32, by = blockIdx.y * 32;
  int tx = threadIdx.x & 31, ty = threadIdx.x >> 5;
#pragma unroll
  for (int i = 0; i < 4; ++i)
    t[ty + i * 8][tx] = X[(size_t)(by + ty + i * 8) * C + bx + tx];
  __syncthreads();
#pragma unroll
  for (int i = 0; i < 4; ++i){
    float v = t[tx][ty + i * 8];
    unsigned short h = f2bf(v);
    size_t o = (size_t)(bx + ty + i * 8) * R + by + tx;
    Th[o] = h; Tl[o] = f2bf(v - bf2f(h));
  }
}

__global__ __launch_bounds__(256) void k_tsplit5(const float* __restrict__ w0, const float* __restrict__ w1,
                                                 const float* __restrict__ w2, const float* __restrict__ w3,
                                                 const float* __restrict__ w4,
                                                 unsigned short* __restrict__ Th, unsigned short* __restrict__ Tl){
  const float* X = (blockIdx.z == 0) ? w0 : (blockIdx.z == 1) ? w1 : (blockIdx.z == 2) ? w2 :
                   (blockIdx.z == 3) ? w3 : w4;
  unsigned short* th = Th + (size_t)blockIdx.z * 65536;
  unsigned short* tl = Tl + (size_t)blockIdx.z * 65536;
  __shared__ float t[32][33];
  int bx = blockIdx.x * 32, by = blockIdx.y * 32;
  int tx = threadIdx.x & 31, ty = threadIdx.x >> 5;
#pragma unroll
  for (int i = 0; i < 4; ++i)
    t[ty + i * 8][tx] = X[(size_t)(by + ty + i * 8) * 256 + bx + tx];
  __syncthreads();
#pragma unroll
  for (int i = 0; i < 4; ++i){
    float v = t[tx][ty + i * 8];
    unsigned short h = f2bf(v);
    size_t o = (size_t)(bx + ty + i * 8) * 256 + by + tx;
    th[o] = h; tl[o] = f2bf(v - bf2f(h));
  }
}

__global__ void k_score(const float* __restrict__ x, const float* __restrict__ w,
                        float* __restrict__ score){
  int row = blockIdx.x;
  float wv = w[threadIdx.x];
  float xv = x[(size_t)row * HID + threadIdx.x];
  float d = waveReduceSum(xv * wv);
  float q = waveReduceSum(wv * wv);
  __shared__ float sd[4], sq[4];
  int lane = threadIdx.x & 63, wd = threadIdx.x >> 6;
  if (!lane){ sd[wd] = d; sq[wd] = q; }
  __syncthreads();
  if (!threadIdx.x)
    score[row] = tanhf((sd[0] + sd[1] + sd[2] + sd[3]) / sqrtf(sq[0] + sq[1] + sq[2] + sq[3]));
}

__global__ void k_topk(const float* __restrict__ score, int n, int k,
                       int* __restrict__ perm, int* __restrict__ inv){
  int i = blockIdx.x; float si = score[i];
  int cnt = 0;
  for (int j = threadIdx.x; j < n; j += 256){
    float sj = score[j];
    if (sj > si || (sj == si && j < i)) cnt++;
  }
#pragma unroll
  for (int off = 32; off > 0; off >>= 1) cnt += __shfl_down(cnt, off);
  __shared__ int sh[4];
  int lane = threadIdx.x & 63, wid = threadIdx.x >> 6;
  if (lane == 0) sh[wid] = cnt;
  __syncthreads();
  if (threadIdx.x == 0){
    int rank = sh[0] + sh[1] + sh[2] + sh[3];
    if (rank < k){ perm[rank] = i; inv[i] = rank; }
    else inv[i] = -1;
  }
}

__global__ void k_pool_x2(const float* __restrict__ x, const float* __restrict__ score,
                          const int* __restrict__ perm,
                          unsigned short* __restrict__ xh, unsigned short* __restrict__ xl, int C){
  int r = blockIdx.x; int pr = perm[r]; float s = score[pr];
  for (int c = threadIdx.x; c < C; c += 256){
    float v = x[(size_t)pr * C + c] * s;
    unsigned short h = f2bf(v);
    xh[(size_t)r * C + c] = h;
    xl[(size_t)r * C + c] = f2bf(v - bf2f(h));
  }
}

template<int SRCL, int OUTL>
__global__ void k_grow_b(const unsigned short* __restrict__ Sh, const unsigned short* __restrict__ Sl,
                         const int* __restrict__ perm,
                         unsigned short* __restrict__ Dh, unsigned short* __restrict__ Dl, int n){
  int r = blockIdx.x, pr = perm[r];
  for (int c = threadIdx.x; c < n; c += 256){
    float v = bf2f(Sh[(size_t)pr * n + c]);
    if (SRCL) v += bf2f(Sl[(size_t)pr * n + c]);
    if (pr == c) v += 1.f;
    unsigned short h = f2bf(v);
    Dh[(size_t)r * n + c] = h;
    if (OUTL) Dl[(size_t)r * n + c] = f2bf(v - bf2f(h));
  }
}

__global__ void k_unpool_split(const float* __restrict__ res, const float* __restrict__ xs,
                               const int* __restrict__ inv,
                               unsigned short* __restrict__ xh, unsigned short* __restrict__ xl){
  int r = blockIdx.x; int ir = inv[r];
  int c = threadIdx.x;
  float v = res[(size_t)r * HID + c];
  if (ir >= 0) v += xs[(size_t)ir * HID + c];
  unsigned short h = f2bf(v);
  xh[(size_t)r * HID + c] = h;
  xl[(size_t)r * HID + c] = f2bf(v - bf2f(h));
}

// ---------------- host orchestration ----------------
extern "C" void kernel_launch(void* const* d_in, const int* in_sizes, int n_in,
                              void* d_out, int out_size, void* d_ws, size_t ws_size,
                              hipStream_t stream){
  (void)in_sizes; (void)n_in; (void)out_size;
  const float* x_in = (const float*)d_in[0];
  const int*   ei   = (const int*)d_in[1];
  const float* dW0 = (const float*)d_in[2];
  const float* dW1 = (const float*)d_in[3];
  const float* dW2 = (const float*)d_in[4];
  const float* dW3 = (const float*)d_in[5];
  const float* db0 = (const float*)d_in[6];
  const float* db1 = (const float*)d_in[7];
  const float* db2 = (const float*)d_in[8];
  const float* db3 = (const float*)d_in[9];
  const float* pw0 = (const float*)d_in[10];
  const float* pw1 = (const float*)d_in[11];
  const float* pw2 = (const float*)d_in[12];
  const float* uW0 = (const float*)d_in[13];
  const float* uW1 = (const float*)d_in[14];
  const float* uW2 = (const float*)d_in[15];
  const float* ub0 = (const float*)d_in[16];
  const float* ub1 = (const float*)d_in[17];
  const float* ub2 = (const float*)d_in[18];

  char* p = (char*)d_ws;
  auto alloc = [&](size_t nbytes) -> void* {
    void* q = (void*)p; p += (nbytes + 255) & ~(size_t)255; return q;
  };
  unsigned* bits = (unsigned*)alloc((size_t)4096 * 128 * 4);
  int* ell = (int*)alloc((size_t)4096 * ECAP * 4);
  int* cnt = (int*)alloc(4096 * 4);
  int* inv1 = (int*)alloc(4096 * 4);
  int* inv2 = (int*)alloc(2048 * 4);
  int* inv3 = (int*)alloc(1024 * 4);
  unsigned char* Rb = (unsigned char*)alloc((size_t)4096 * 2048);
  unsigned short* A1h = (unsigned short*)alloc((size_t)2048 * 2048 * 2);
  unsigned short* A1T = (unsigned short*)alloc((size_t)2048 * 2048 * 2);
  unsigned short* A2h = (unsigned short*)alloc((size_t)1024 * 1024 * 2);
  unsigned short* A2l = (unsigned short*)alloc((size_t)1024 * 1024 * 2);
  unsigned short* A2Th = (unsigned short*)alloc((size_t)1024 * 1024 * 2);
  unsigned short* A2Tl = (unsigned short*)alloc((size_t)1024 * 1024 * 2);
  unsigned short* A3h = (unsigned short*)alloc((size_t)512 * 512 * 2);
  unsigned short* A3l = (unsigned short*)alloc((size_t)512 * 512 * 2);
  unsigned short* Lb2h = (unsigned short*)alloc((size_t)1024 * 2048 * 2);
  unsigned short* Rt2h = (unsigned short*)alloc((size_t)1024 * 2048 * 2);
  unsigned short* Lb3h = (unsigned short*)alloc((size_t)512 * 1024 * 2);
  unsigned short* Lb3l = (unsigned short*)alloc((size_t)512 * 1024 * 2);
  unsigned short* Rt3h = (unsigned short*)alloc((size_t)512 * 1024 * 2);
  unsigned short* Rt3l = (unsigned short*)alloc((size_t)512 * 1024 * 2);
  unsigned short* xinh = (unsigned short*)alloc((size_t)4096 * 512 * 2);
  unsigned short* xinl = (unsigned short*)alloc((size_t)4096 * 512 * 2);
  float* x0 = (float*)alloc((size_t)4096 * HID * 4);
  float* x1 = (float*)alloc((size_t)2048 * HID * 4);
  float* x2 = (float*)alloc((size_t)1024 * HID * 4);
  float* xv = (float*)alloc((size_t)2048 * HID * 4);
  unsigned short* xuh = (unsigned short*)alloc((size_t)4096 * HID * 2);
  unsigned short* xul = (unsigned short*)alloc((size_t)4096 * HID * 2);
  unsigned short* xph = (unsigned short*)alloc((size_t)2048 * HID * 2);
  unsigned short* xpl = (unsigned short*)alloc((size_t)2048 * HID * 2);
  unsigned short* W0th = (unsigned short*)alloc((size_t)256 * 512 * 2);
  unsigned short* W0tl = (unsigned short*)alloc((size_t)256 * 512 * 2);
  unsigned short* W5th = (unsigned short*)alloc((size_t)5 * 256 * 256 * 2);
  unsigned short* W5tl = (unsigned short*)alloc((size_t)5 * 256 * 256 * 2);
  unsigned short* W2th = (unsigned short*)alloc((size_t)64 * 256 * 2);
  unsigned short* W2tl = (unsigned short*)alloc((size_t)64 * 256 * 2);
  float* Zs  = (float*)alloc((size_t)4096 * HID * 4);
  unsigned short* ZsTh = (unsigned short*)alloc((size_t)256 * 2048 * 2);
  unsigned short* ZsTl = (unsigned short*)alloc((size_t)256 * 2048 * 2);
  float* dinv0 = (float*)alloc(4096 * 4);
  float* dinv1 = (float*)alloc(2048 * 4);
  float* dinv2 = (float*)alloc(1024 * 4);
  float* dinv3 = (float*)alloc(512 * 4);
  float* score = (float*)alloc(4096 * 4);
  int* perm1 = (int*)alloc(2048 * 4);
  int* perm2 = (int*)alloc(1024 * 4);
  int* perm3 = (int*)alloc(512 * 4);
  if ((size_t)(p - (char*)d_ws) > ws_size) return;

  // ---- weight prep ----
  { dim3 g(8, 16); k_tsplit<<<g, 256, 0, stream>>>(dW0, IN_DIM, HID, W0th, W0tl); }
  { dim3 g(8, 8, 5); k_tsplit5<<<g, 256, 0, stream>>>(dW1, dW2, dW3, uW0, uW1, W5th, W5tl); }
  { dim3 g(2, 8); k_tsplit<<<g, 256, 0, stream>>>(uW2, HID, OUT_DIM, W2th, W2tl); }

  // ---- graph build ----
  hipMemsetAsync(bits, 0, (size_t)4096 * 128 * 4, stream);
  k_build_bits<<<EE / 256, 256, 0, stream>>>(ei, bits);
  k_ell<<<4096, 128, 0, stream>>>(bits, ell, cnt, dinv0);

  // ---- conv0 (score fused into spmm) ----
  k_split<<<(4096 * 512 + 255) / 256, 256, 0, stream>>>(x_in, xinh, xinl, 4096 * 512);
  { dim3 g(4, 64);
    k_mm<1,1,0,2><<<g, 256, 0, stream>>>(xinh, xinl, W0th, W0tl, 4096, HID, IN_DIM,
                                         Zs, nullptr, nullptr, dinv0, nullptr, nullptr, 0); }
  k_spmm_ell<256,1,1><<<4096, 256, 0, stream>>>(ell, cnt, Zs, dinv0, db0, x0, pw0, score);

  // ---- pool 1 (4096 -> 2048) ----
  k_topk<<<4096, 256, 0, stream>>>(score, 4096, 2048, perm1, inv1);
  k_pool_x2<<<2048, 256, 0, stream>>>(x0, score, perm1, xph, xpl, HID);
  k_build_Rb<<<4096, 256, 0, stream>>>(ell, cnt, inv1, Rb);
  k_sq1<<<2048, 256, 0, stream>>>(ell, cnt, perm1, Rb, A1h, dinv1);
  // conv1
  { dim3 g(4, 32);
    k_mm<1,1,0,4><<<g, 256, 0, stream>>>(xph, xpl, W5th, W5tl, 2048, HID, HID,
                                         Zs, ZsTh, ZsTl, dinv1, nullptr, nullptr, 0); }
  { dim3 g(4, 32);
    k_mm<0,1,0,3><<<g, 256, 0, stream>>>(A1h, nullptr, ZsTh, ZsTl, 2048, HID, 2048,
                                         x1, nullptr, nullptr, dinv1, Zs, db1, 1); }

  // ---- pool 2 (2048 -> 1024) ----
  k_score<<<2048, 256, 0, stream>>>(x1, pw1, score);
  k_topk<<<2048, 256, 0, stream>>>(score, 2048, 1024, perm2, inv2);
  { dim3 g(64, 64); k_tr_b<0><<<g, 256, 0, stream>>>(A1h, nullptr, A1T, nullptr, 2048, 2048); }
  k_grow_b<0,0><<<1024, 256, 0, stream>>>(A1h, nullptr, perm2, Lb2h, nullptr, 2048);
  k_grow_b<0,0><<<1024, 256, 0, stream>>>(A1T, nullptr, perm2, Rt2h, nullptr, 2048);
  { dim3 g(16, 16);
    k_mm<0,0,0,1><<<g, 256, 0, stream>>>(Lb2h, nullptr, Rt2h, nullptr, 1024, 1024, 2048,
                                         nullptr, A2h, A2l, nullptr, nullptr, nullptr, 1); }
  k_dinv_bf<1><<<1024, 256, 0, stream>>>(A2h, A2l, dinv2, 1024);
  k_pool_x2<<<1024, 256, 0, stream>>>(x1, score, perm2, xph, xpl, HID);
  // conv2
  { dim3 g(4, 16);
    k_mm<1,1,0,4><<<g, 256, 0, stream>>>(xph, xpl, W5th + 65536, W5tl + 65536, 1024, HID, HID,
                                         Zs, ZsTh, ZsTl, dinv2, nullptr, nullptr, 0); }
  { dim3 g(4, 16);
    k_mm<1,1,0,3><<<g, 256, 0, stream>>>(A2h, A2l, ZsTh, ZsTl, 1024, HID, 1024,
                                         x2, nullptr, nullptr, dinv2, Zs, db2, 1); }

  // ---- pool 3 (1024 -> 512) ----
  k_score<<<1024, 256, 0, stream>>>(x2, pw2, score);
  k_topk<<<1024, 256, 0, stream>>>(score, 1024, 512, perm3, inv3);
  { dim3 g(32, 32); k_tr_b<1><<<g, 256, 0, stream>>>(A2h, A2l, A2Th, A2Tl, 1024, 1024); }
  k_grow_b<1,1><<<512, 256, 0, stream>>>(A2h, A2l, perm3, Lb3h, Lb3l, 1024);
  k_grow_b<1,1><<<512, 256, 0, stream>>>(A2Th, A2Tl, perm3, Rt3h, Rt3l, 1024);
  { dim3 g(8, 8);
    k_mm<1,1,1,1><<<g, 256, 0, stream>>>(Lb3h, Lb3l, Rt3h, Rt3l, 512, 512, 1024,
                                         nullptr, A3h, A3l, nullptr, nullptr, nullptr, 1); }
  k_dinv_bf<1><<<512, 256, 0, stream>>>(A3h, A3l, dinv3, 512);
  k_pool_x2<<<512, 256, 0, stream>>>(x2, score, perm3, xph, xpl, HID);
  // conv3
  { dim3 g(4, 8);
    k_mm<1,1,0,4><<<g, 256, 0, stream>>>(xph, xpl, W5th + 2 * 65536, W5tl + 2 * 65536, 512, HID, HID,
                                         Zs, ZsTh, ZsTl, dinv3, nullptr, nullptr, 0); }
  { dim3 g(4, 8);
    k_mm<1,1,0,3><<<g, 256, 0, stream>>>(A3h, A3l, ZsTh, ZsTl, 512, HID, 512,
                                         xv, nullptr, nullptr, dinv3, Zs, db3, 1); }   // xv = x3

  // ---- up 0 (res=x2, inv3, A2) ----
  k_unpool_split<<<1024, 256, 0, stream>>>(x2, xv, inv3, xuh, xul);
  { dim3 g(4, 16);
    k_mm<1,1,0,4><<<g, 256, 0, stream>>>(xuh, xul, W5th + 3 * 65536, W5tl + 3 * 65536, 1024, HID, HID,
                                         Zs, ZsTh, ZsTl, dinv2, nullptr, nullptr, 0); }
  { dim3 g(4, 16);
    k_mm<1,1,0,3><<<g, 256, 0, stream>>>(A2h, A2l, ZsTh, ZsTl, 1024, HID, 1024,
                                         xv, nullptr, nullptr, dinv2, Zs, ub0, 1); }

  // ---- up 1 (res=x1, inv2, A1) ----
  k_unpool_split<<<2048, 256, 0, stream>>>(x1, xv, inv2, xuh, xul);
  { dim3 g(4, 32);
    k_mm<1,1,0,4><<<g, 256, 0, stream>>>(xuh, xul, W5th + 4 * 65536, W5tl + 4 * 65536, 2048, HID, HID,
                                         Zs, ZsTh, ZsTl, dinv1, nullptr, nullptr, 0); }
  { dim3 g(4, 32);
    k_mm<0,1,0,3><<<g, 256, 0, stream>>>(A1h, nullptr, ZsTh, ZsTl, 2048, HID, 2048,
                                         xv, nullptr, nullptr, dinv1, Zs, ub1, 1); }

  // ---- up 2 (res=x0, inv1, A0 sparse, Cout=64, no relu) ----
  k_unpool_split<<<4096, 256, 0, stream>>>(x0, xv, inv1, xuh, xul);
  { dim3 g(1, 64);
    k_mm<1,1,0,2><<<g, 256, 0, stream>>>(xuh, xul, W2th, W2tl, 4096, OUT_DIM, HID,
                                         Zs, nullptr, nullptr, dinv0, nullptr, nullptr, 0); }
  k_spmm_ell<64,0,0><<<4096, 256, 0, stream>>>(ell, cnt, Zs, dinv0, ub2, (float*)d_out, nullptr, nullptr);
}

// Round 7
// 243.762 us; speedup vs baseline: 1.3019x; 1.3019x over previous
//
#include <hip/hip_runtime.h>
#include <math.h>

#define NN 4096
#define EE 131072
#define IN_DIM 512
#define HID 256
#define OUT_DIM 64
#define ECAP 128

typedef __attribute__((ext_vector_type(8))) short bf8_t;
typedef __attribute__((ext_vector_type(4))) float f4_t;
typedef __attribute__((ext_vector_type(8))) unsigned short us8_t;

#define GAS __attribute__((address_space(1)))
#define LAS __attribute__((address_space(3)))

// ---------------- bf16 helpers (RNE) ----------------
__device__ __forceinline__ unsigned short f2bf(float v){
  union { float f; unsigned u; } x; x.f = v;
  unsigned r = x.u + 0x7fffu + ((x.u >> 16) & 1u);
  return (unsigned short)(r >> 16);
}
__device__ __forceinline__ float bf2f(unsigned short h){
  union { float f; unsigned u; } x; x.u = ((unsigned)h) << 16;
  return x.f;
}

__device__ __forceinline__ float waveReduceSum(float v){
#pragma unroll
  for (int off = 32; off > 0; off >>= 1) v += __shfl_down(v, off);
  return v;
}

// ---------------- mega-prep: zero bits + split x_in + transpose-split all weights ----------------
__global__ __launch_bounds__(256) void k_prep(
    const float* __restrict__ x_in, const float* __restrict__ dW0,
    const float* __restrict__ dW1, const float* __restrict__ dW2,
    const float* __restrict__ dW3, const float* __restrict__ uW0,
    const float* __restrict__ uW1, const float* __restrict__ uW2,
    unsigned* __restrict__ bits,
    unsigned short* __restrict__ xinh, unsigned short* __restrict__ xinl,
    unsigned short* __restrict__ W0th, unsigned short* __restrict__ W0tl,
    unsigned short* __restrict__ W5th, unsigned short* __restrict__ W5tl,
    unsigned short* __restrict__ W2th, unsigned short* __restrict__ W2tl)
{
  int b = blockIdx.x;
  if (b < 128){                       // zero 2MB bit-adjacency
    int base = b * 4096 + threadIdx.x;
#pragma unroll
    for (int i = 0; i < 16; ++i) bits[base + i * 256] = 0;
    return;
  }
  b -= 128;
  if (b < 2048){                      // split x_in (4096x512 fp32 -> bf16 hi/lo)
    int i0 = b * 1024 + threadIdx.x;
#pragma unroll
    for (int i = 0; i < 4; ++i){
      int idx = i0 + i * 256;
      float v = x_in[idx];
      unsigned short h = f2bf(v);
      xinh[idx] = h; xinl[idx] = f2bf(v - bf2f(h));
    }
    return;
  }
  b -= 2048;
  const float* X; unsigned short *Th, *Tl; int R, C, tile;
  if (b < 128){ X = dW0; Th = W0th; Tl = W0tl; R = 512; C = 256; tile = b; }
  else if (b < 448){
    int t2 = b - 128; int z = t2 >> 6; int rem = t2 & 63;
    const float* ws[5] = {dW1, dW2, dW3, uW0, uW1};
    X = ws[z]; Th = W5th + (size_t)z * 65536; Tl = W5tl + (size_t)z * 65536;
    R = 256; C = 256; tile = rem;
  } else { X = uW2; Th = W2th; Tl = W2tl; R = 256; C = 64; tile = b - 448; }
  int tpr = C >> 5;
  int bx = (tile % tpr) * 32, by = (tile / tpr) * 32;
  __shared__ float t[32][33];
  int tx = threadIdx.x & 31, ty = threadIdx.x >> 5;
#pragma unroll
  for (int i = 0; i < 4; ++i)
    t[ty + i * 8][tx] = X[(size_t)(by + ty + i * 8) * C + bx + tx];
  __syncthreads();
#pragma unroll
  for (int i = 0; i < 4; ++i){
    float v = t[tx][ty + i * 8];
    unsigned short h = f2bf(v);
    size_t o = (size_t)(bx + ty + i * 8) * R + by + tx;
    Th[o] = h; Tl[o] = f2bf(v - bf2f(h));
  }
}

// ---------------- graph build: bitmask + ELL ----------------
__global__ void k_build_bits(const int* __restrict__ ei, unsigned* __restrict__ bits){
  int e = blockIdx.x * blockDim.x + threadIdx.x;
  if (e < EE){
    int r = ei[e], c = ei[EE + e];
    atomicOr(&bits[r * 128 + (c >> 5)], 1u << (c & 31));
  }
}

__global__ __launch_bounds__(128) void k_ell(const unsigned* __restrict__ bits,
                                             int* __restrict__ ell, int* __restrict__ cnt,
                                             float* __restrict__ dinv){
  int r = blockIdx.x, t = threadIdx.x;
  unsigned w = bits[r * 128 + t];
  int c = __popc(w);
  __shared__ int sc[128];
  sc[t] = c; __syncthreads();
  for (int off = 1; off < 128; off <<= 1){
    int a = sc[t], b = (t >= off) ? sc[t - off] : 0;
    __syncthreads(); sc[t] = a + b; __syncthreads();
  }
  int total = sc[127];
  int pos = sc[t] - c;
  int base = r * ECAP;
  while (w){
    int b = __ffs(w) - 1; w &= w - 1;
    if (pos < ECAP) ell[base + pos] = t * 32 + b;
    pos++;
  }
  if (t == 0){
    cnt[r] = (total < ECAP) ? total : ECAP;
    dinv[r] = 1.0f / sqrtf((float)total + 2.0f);
  }
}

// ---------------- fused SpMM (ELL, values==1) + GCN epilogue (+ optional score) ----------------
template<int NCOLS, int RELU, int SC>
__global__ __launch_bounds__(256) void k_spmm_ell(
    const int* __restrict__ ell, const int* __restrict__ cnt,
    const float* __restrict__ Zs, const float* __restrict__ dinv,
    const float* __restrict__ bias, float* __restrict__ out,
    const float* __restrict__ scw, float* __restrict__ score)
{
  int r = blockIdx.x;
  __shared__ int s_idx[ECAP];
  __shared__ int s_n;
  __shared__ float sh[4 * NCOLS];
  __shared__ float sd[4], sq[4];
  if (threadIdx.x == 0) s_n = cnt[r];
  for (int i = threadIdx.x; i < ECAP; i += 256) s_idx[i] = ell[r * ECAP + i];
  __syncthreads();
  int n = s_n; if (n > ECAP) n = ECAP;
  int wv = threadIdx.x >> 6, lane = threadIdx.x & 63;
  if (NCOLS == 256){
    f4_t acc = (f4_t){0.f, 0.f, 0.f, 0.f};
    for (int e = wv; e < n; e += 4){
      const f4_t* row = (const f4_t*)(Zs + (size_t)s_idx[e] * 256);
      acc += row[lane];
    }
    ((f4_t*)(sh + wv * 256))[lane] = acc;
  } else {
    float acc = 0.f;
    for (int e = wv; e < n; e += 4)
      acc += Zs[(size_t)s_idx[e] * 64 + lane];
    sh[wv * 64 + lane] = acc;
  }
  __syncthreads();
  int t = threadIdx.x;
  float o = 0.f;
  if (t < NCOLS){
    float y = sh[t] + sh[NCOLS + t] + sh[2 * NCOLS + t] + sh[3 * NCOLS + t];
    float z = Zs[(size_t)r * NCOLS + t];
    o = dinv[r] * (y + 2.0f * z) + bias[t];
    if (RELU) o = fmaxf(o, 0.f);
    out[(size_t)r * NCOLS + t] = o;
  }
  if (SC){
    float w = scw[t];
    float d = waveReduceSum(o * w);
    float q = waveReduceSum(w * w);
    if (!lane){ sd[wv] = d; sq[wv] = q; }
    __syncthreads();
    if (!t) score[r] = tanhf((sd[0] + sd[1] + sd[2] + sd[3]) / sqrtf(sq[0] + sq[1] + sq[2] + sq[3]));
  }
}

// ---------------- pool1: pool_x2 + build_Rb + xu1 non-selected fill (one dispatch) ----------------
__global__ __launch_bounds__(256) void k_pool_build(
    const float* __restrict__ x0, const float* __restrict__ score,
    const int* __restrict__ perm1, const int* __restrict__ inv1,
    const int* __restrict__ ell, const int* __restrict__ cnt,
    unsigned short* __restrict__ xph, unsigned short* __restrict__ xpl,
    unsigned char* __restrict__ Rb,
    unsigned short* __restrict__ xu1h, unsigned short* __restrict__ xu1l)
{
  int b = blockIdx.x;
  if (b < 2048){                           // gated pooled features
    int pr = perm1[b]; float s = score[pr];
    int c = threadIdx.x;
    float v = x0[(size_t)pr * 256 + c] * s;
    unsigned short h = f2bf(v);
    xph[(size_t)b * 256 + c] = h;
    xpl[(size_t)b * 256 + c] = f2bf(v - bf2f(h));
    return;
  }
  if (b < 6144){                           // Rb[k][s] = (A0+I)[k][perm1[s]] u8
    int k = b - 2048;
    __shared__ unsigned char row[2048];
    for (int i = threadIdx.x; i < 512; i += 256) ((int*)row)[i] = 0;
    __syncthreads();
    int n = cnt[k];
    for (int e = threadIdx.x; e < n; e += 256){
      int s = inv1[ell[k * ECAP + e]];
      if (s >= 0) row[s] = 1;
    }
    __syncthreads();
    if (threadIdx.x == 0){
      int sk = inv1[k];
      if (sk >= 0) row[sk] += 1;
    }
    __syncthreads();
    *(uint2*)(Rb + (size_t)k * 2048 + threadIdx.x * 8) = *(uint2*)(row + threadIdx.x * 8);
    return;
  }
  int r = b - 6144;                        // xu1 fill: non-selected rows = x0
  if (inv1[r] < 0){
    int c = threadIdx.x;
    float v = x0[(size_t)r * 256 + c];
    unsigned short h = f2bf(v);
    xu1h[(size_t)r * 256 + c] = h;
    xu1l[(size_t)r * 256 + c] = f2bf(v - bf2f(h));
  }
}

// ---------------- pool2/3: pool_x2 + xu fill ----------------
__global__ __launch_bounds__(256) void k_pool_fill(
    const float* __restrict__ x, const float* __restrict__ score,
    const int* __restrict__ perm, const int* __restrict__ inv, int k,
    unsigned short* __restrict__ xph, unsigned short* __restrict__ xpl,
    unsigned short* __restrict__ xuh, unsigned short* __restrict__ xul)
{
  int b = blockIdx.x, c = threadIdx.x;
  if (b < k){
    int pr = perm[b]; float s = score[pr];
    float v = x[(size_t)pr * 256 + c] * s;
    unsigned short h = f2bf(v);
    xph[(size_t)b * 256 + c] = h;
    xpl[(size_t)b * 256 + c] = f2bf(v - bf2f(h));
  } else {
    int r = b - k;
    if (inv[r] < 0){
      float v = x[(size_t)r * 256 + c];
      unsigned short h = f2bf(v);
      xuh[(size_t)r * 256 + c] = h;
      xul[(size_t)r * 256 + c] = f2bf(v - bf2f(h));
    }
  }
}

// ---------------- pool-1 squaring from ELL (u8 Rb) ----------------
__global__ __launch_bounds__(256) void k_sq1(const int* __restrict__ ell, const int* __restrict__ cnt,
                                             const int* __restrict__ perm,
                                             const unsigned char* __restrict__ Rb,
                                             unsigned short* __restrict__ A1h,
                                             float* __restrict__ dinv1){
  int r = blockIdx.x;
  int pr = perm[r];
  __shared__ int s_idx[ECAP];
  __shared__ int s_n;
  __shared__ float sred[4];
  if (threadIdx.x == 0) s_n = cnt[pr];
  for (int i = threadIdx.x; i < ECAP; i += 256) s_idx[i] = ell[pr * ECAP + i];
  __syncthreads();
  int n = s_n; if (n > ECAP) n = ECAP;
  int colb = threadIdx.x * 8;
  uint2 acc = *(const uint2*)(Rb + (size_t)pr * 2048 + colb);
  for (int e = 0; e < n; ++e){
    uint2 v = *(const uint2*)(Rb + (size_t)s_idx[e] * 2048 + colb);
    acc.x += v.x; acc.y += v.y;   // bytewise, no carries (values <=130)
  }
  float fs = 0.f;
  us8_t o;
#pragma unroll
  for (int j = 0; j < 8; ++j){
    unsigned byte = ((j < 4 ? acc.x : acc.y) >> (8 * (j & 3))) & 0xFFu;
    if (colb + j == r) byte = 0;
    float f = (float)byte;
    fs += f;
    o[j] = f2bf(f);
  }
  *(us8_t*)(A1h + (size_t)r * 2048 + colb) = o;
  fs = waveReduceSum(fs);
  int lane = threadIdx.x & 63, wd = threadIdx.x >> 6;
  if (!lane) sred[wd] = fs;
  __syncthreads();
  if (!threadIdx.x)
    dinv1[r] = 1.0f / sqrtf(sred[0] + sred[1] + sred[2] + sred[3] + 2.0f);
}

// ---------------- bf16 transpose (h [+l]) ----------------
template<int TWO>
__global__ __launch_bounds__(256) void k_tr_b(const unsigned short* __restrict__ Sh,
                                              const unsigned short* __restrict__ Sl,
                                              unsigned short* __restrict__ Dh,
                                              unsigned short* __restrict__ Dl, int R, int C){
  __shared__ unsigned short th[32][33];
  __shared__ unsigned short tl[TWO ? 32 : 1][TWO ? 33 : 1];
  int bx = blockIdx.x * 32, by = blockIdx.y * 32;
  int tx = threadIdx.x & 31, ty = threadIdx.x >> 5;
#pragma unroll
  for (int i = 0; i < 4; ++i){
    th[ty + i * 8][tx] = Sh[(size_t)(by + ty + i * 8) * C + bx + tx];
    if (TWO) tl[ty + i * 8][tx] = Sl[(size_t)(by + ty + i * 8) * C + bx + tx];
  }
  __syncthreads();
#pragma unroll
  for (int i = 0; i < 4; ++i){
    size_t o = (size_t)(bx + ty + i * 8) * R + by + tx;
    Dh[o] = th[tx][ty + i * 8];
    if (TWO) Dl[o] = tl[tx][ty + i * 8];
  }
}

// ---------------- grow L and R halves in one dispatch ----------------
template<int SRCL, int OUTL>
__global__ void k_grow2(const unsigned short* __restrict__ Sh, const unsigned short* __restrict__ Sl,
                        const unsigned short* __restrict__ Th, const unsigned short* __restrict__ Tl,
                        const int* __restrict__ perm,
                        unsigned short* __restrict__ Lh, unsigned short* __restrict__ Ll,
                        unsigned short* __restrict__ Rh, unsigned short* __restrict__ Rl,
                        int n, int half)
{
  int b = blockIdx.x;
  const unsigned short *sh, *sl; unsigned short *dh, *dl; int r;
  if (b < half){ r = b; sh = Sh; sl = Sl; dh = Lh; dl = Ll; }
  else { r = b - half; sh = Th; sl = Tl; dh = Rh; dl = Rl; }
  int pr = perm[r];
  for (int c = threadIdx.x; c < n; c += 256){
    float v = bf2f(sh[(size_t)pr * n + c]);
    if (SRCL) v += bf2f(sl[(size_t)pr * n + c]);
    if (pr == c) v += 1.f;
    unsigned short h = f2bf(v);
    dh[(size_t)r * n + c] = h;
    if (OUTL) dl[(size_t)r * n + c] = f2bf(v - bf2f(h));
  }
}

// ---------------- MFMA GEMM: global_load_lds double-buffered ----------------
// EPI 0: write fp32 partial P[z][M][N] (split-K)
// EPI 2: Cf = dinv[row]*acc
// EPI 4: sv = dinv[row]*acc; Cf = sv; Ch/Cl[col*M+row] = split(sv)  (transposed split)
template<int HAS_AL, int HAS_BL, int HAS_LL, int EPI>
__global__ __launch_bounds__(256) void k_mm(
    const unsigned short* __restrict__ Ah, const unsigned short* __restrict__ Al,
    const unsigned short* __restrict__ Bh, const unsigned short* __restrict__ Bl,
    int M, int N, int K, int KS, float* __restrict__ P,
    float* __restrict__ Cf, unsigned short* __restrict__ Ch, unsigned short* __restrict__ Cl,
    const float* __restrict__ dinv)
{
  constexpr int NARR = 2 + HAS_AL + HAS_BL;
  constexpr int BUF = NARR * 8192;
  __shared__ int4 ldsq[NARR * 512 * 2];
  char* ldsc = (char*)ldsq;

  const int tid = threadIdx.x, lane = tid & 63, wid = tid >> 6;
  const int wm = wid >> 1, wn = wid & 1;
  const int bm = blockIdx.y << 6, bn = blockIdx.x << 6;
  const int z = blockIdx.z;
  const int l15 = lane & 15, l4 = lane >> 4;

  f4_t acc[2][2];
#pragma unroll
  for (int i = 0; i < 2; ++i)
#pragma unroll
    for (int j = 0; j < 2; ++j) acc[i][j] = (f4_t){0.f, 0.f, 0.f, 0.f};

  const size_t rb = (size_t)K * 2;
  const size_t kz = (size_t)z * KS * 2;
  const char* pAh = (const char*)Ah + (size_t)bm * rb;
  const char* pAl = HAS_AL ? (const char*)Al + (size_t)bm * rb : nullptr;
  const char* pBh = (const char*)Bh + (size_t)bn * rb;
  const char* pBl = HAS_BL ? (const char*)Bl + (size_t)bn * rb : nullptr;

  auto stage = [&](int t, int b2){
    char* ldsb = ldsc + b2 * BUF;
    const size_t kb = kz + (size_t)t * 128;
#pragma unroll
    for (int it = 0; it < 2; ++it){
      const int idx = tid + (it << 8);
      const int row = idx >> 3;
      const int kc = ((idx & 7) << 4) ^ ((row & 7) << 4);  // pre-swizzled source col
      const size_t go = (size_t)row * rb + kb + kc;
      const int lo = idx * 16;
      __builtin_amdgcn_global_load_lds((const GAS void*)(pAh + go), (LAS void*)(ldsb + lo), 16, 0, 0);
      __builtin_amdgcn_global_load_lds((const GAS void*)(pBh + go), (LAS void*)(ldsb + 8192 + lo), 16, 0, 0);
      if (HAS_AL)
        __builtin_amdgcn_global_load_lds((const GAS void*)(pAl + go), (LAS void*)(ldsb + 16384 + lo), 16, 0, 0);
      if (HAS_BL)
        __builtin_amdgcn_global_load_lds((const GAS void*)(pBl + go), (LAS void*)(ldsb + (2 + HAS_AL) * 8192 + lo), 16, 0, 0);
    }
  };

  const int T = KS >> 6;
  stage(0, 0);
  int b = 0;
  for (int t = 0; t < T; ++t){
    if (t + 1 < T){
      stage(t + 1, b ^ 1);
      if constexpr (NARR == 2) asm volatile("s_waitcnt vmcnt(4)" ::: "memory");
      else if constexpr (NARR == 3) asm volatile("s_waitcnt vmcnt(6)" ::: "memory");
      else asm volatile("s_waitcnt vmcnt(8)" ::: "memory");
    } else {
      asm volatile("s_waitcnt vmcnt(0)" ::: "memory");
    }
    __syncthreads();
    const char* ldsb = ldsc + b * BUF;
#pragma unroll
    for (int ks = 0; ks < 2; ++ks){
      bf8_t aH[2], aL[2], bH[2], bL[2];
#pragma unroll
      for (int f = 0; f < 2; ++f){
        int ar = wm * 32 + f * 16 + l15;
        int aoff = ar * 128 + (((ks * 64) + (l4 << 4)) ^ ((ar & 7) << 4));
        aH[f] = *(const bf8_t*)(ldsb + aoff);
        if (HAS_AL) aL[f] = *(const bf8_t*)(ldsb + 16384 + aoff);
        int br = wn * 32 + f * 16 + l15;
        int boff = br * 128 + (((ks * 64) + (l4 << 4)) ^ ((br & 7) << 4));
        bH[f] = *(const bf8_t*)(ldsb + 8192 + boff);
        if (HAS_BL) bL[f] = *(const bf8_t*)(ldsb + (2 + HAS_AL) * 8192 + boff);
      }
#pragma unroll
      for (int i = 0; i < 2; ++i)
#pragma unroll
        for (int j = 0; j < 2; ++j){
          acc[i][j] = __builtin_amdgcn_mfma_f32_16x16x32_bf16(aH[i], bH[j], acc[i][j], 0, 0, 0);
          if (HAS_BL) acc[i][j] = __builtin_amdgcn_mfma_f32_16x16x32_bf16(aH[i], bL[j], acc[i][j], 0, 0, 0);
          if (HAS_AL) acc[i][j] = __builtin_amdgcn_mfma_f32_16x16x32_bf16(aL[i], bH[j], acc[i][j], 0, 0, 0);
          if (HAS_LL) acc[i][j] = __builtin_amdgcn_mfma_f32_16x16x32_bf16(aL[i], bL[j], acc[i][j], 0, 0, 0);
        }
    }
    __syncthreads();
    b ^= 1;
  }

  float* Pz = (EPI == 0) ? P + (size_t)z * M * N : nullptr;
#pragma unroll
  for (int i = 0; i < 2; ++i)
#pragma unroll
    for (int j = 0; j < 2; ++j)
#pragma unroll
      for (int r = 0; r < 4; ++r){
        int grow = bm + wm * 32 + i * 16 + l4 * 4 + r;
        int gcol = bn + wn * 32 + j * 16 + l15;
        float v = acc[i][j][r];
        size_t o = (size_t)grow * N + gcol;
        if (EPI == 0){
          Pz[o] = v;
        } else if (EPI == 2){
          Cf[o] = dinv[grow] * v;
        } else { // EPI == 4
          float sv = dinv[grow] * v;
          Cf[o] = sv;
          unsigned short h = f2bf(sv);
          size_t ot = (size_t)gcol * M + grow;
          Ch[ot] = h; Cl[ot] = f2bf(sv - bf2f(h));
        }
      }
}

// ---------------- split-K reduce + fused epilogues (one block per output row) ----------------
// EPI 2: Of = relu?(dinv[row]*(s+2Zs)+bias); optional score (SC, NC==256)
// EPI 3: v = (c==row)?0:s; Oh/Ol = split(v); dout[row] = 1/sqrt(rowsum+2)
// EPI 4: out = relu?(dinv[row]*(s+2Zs)+bias); comb = res[perm[row]]+out; Oh/Ol[perm[row]*NC+c] = split(comb)
template<int EPI, int SC>
__global__ __launch_bounds__(256) void k_red(
    const float* __restrict__ P, int Z, int M, int NC,
    const float* __restrict__ dinv, const float* __restrict__ Zs,
    const float* __restrict__ bias,
    float* __restrict__ Of, unsigned short* __restrict__ Oh, unsigned short* __restrict__ Ol,
    float* __restrict__ dout, int relu,
    const float* __restrict__ scw, float* __restrict__ score,
    const float* __restrict__ res, const int* __restrict__ permsel)
{
  int row = blockIdx.x;
  int prow = (EPI == 4) ? permsel[row] : 0;
  float rsum = 0.f;
  float o_sc = 0.f;
  for (int c = threadIdx.x; c < NC; c += 256){
    size_t o = (size_t)row * NC + c;
    float s = P[o];
    for (int zz = 1; zz < Z; ++zz) s += P[(size_t)zz * M * NC + o];
    if (EPI == 2){
      float out = dinv[row] * (s + 2.0f * Zs[o]) + bias[c];
      if (relu) out = fmaxf(out, 0.f);
      Of[o] = out;
      o_sc = out;
    } else if (EPI == 3){
      float v = (c == row) ? 0.f : s;
      unsigned short h = f2bf(v);
      Oh[o] = h; Ol[o] = f2bf(v - bf2f(h));
      rsum += v;
    } else { // EPI == 4
      float out = dinv[row] * (s + 2.0f * Zs[o]) + bias[c];
      if (relu) out = fmaxf(out, 0.f);
      float comb = res[(size_t)prow * NC + c] + out;
      unsigned short h = f2bf(comb);
      size_t od = (size_t)prow * NC + c;
      Oh[od] = h; Ol[od] = f2bf(comb - bf2f(h));
    }
  }
  int lane = threadIdx.x & 63, wd = threadIdx.x >> 6;
  if (EPI == 3){
    rsum = waveReduceSum(rsum);
    __shared__ float sr[4];
    if (!lane) sr[wd] = rsum;
    __syncthreads();
    if (!threadIdx.x) dout[row] = 1.0f / sqrtf(sr[0] + sr[1] + sr[2] + sr[3] + 2.0f);
  }
  if (SC){
    float w = scw[threadIdx.x];
    float d = waveReduceSum(o_sc * w);
    float q = waveReduceSum(w * w);
    __shared__ float sd[4], sq[4];
    if (!lane){ sd[wd] = d; sq[wd] = q; }
    __syncthreads();
    if (!threadIdx.x)
      score[row] = tanhf((sd[0] + sd[1] + sd[2] + sd[3]) / sqrtf(sq[0] + sq[1] + sq[2] + sq[3]));
  }
}

// ---------------- topk (stable descending rank) ----------------
__global__ void k_topk(const float* __restrict__ score, int n, int k,
                       int* __restrict__ perm, int* __restrict__ inv){
  int i = blockIdx.x; float si = score[i];
  int cnt = 0;
  for (int j = threadIdx.x; j < n; j += 256){
    float sj = score[j];
    if (sj > si || (sj == si && j < i)) cnt++;
  }
#pragma unroll
  for (int off = 32; off > 0; off >>= 1) cnt += __shfl_down(cnt, off);
  __shared__ int sh[4];
  int lane = threadIdx.x & 63, wid = threadIdx.x >> 6;
  if (lane == 0) sh[wid] = cnt;
  __syncthreads();
  if (threadIdx.x == 0){
    int rank = sh[0] + sh[1] + sh[2] + sh[3];
    if (rank < k){ perm[rank] = i; inv[i] = rank; }
    else inv[i] = -1;
  }
}

// ---------------- host orchestration ----------------
extern "C" void kernel_launch(void* const* d_in, const int* in_sizes, int n_in,
                              void* d_out, int out_size, void* d_ws, size_t ws_size,
                              hipStream_t stream){
  (void)in_sizes; (void)n_in; (void)out_size;
  const float* x_in = (const float*)d_in[0];
  const int*   ei   = (const int*)d_in[1];
  const float* dW0 = (const float*)d_in[2];
  const float* dW1 = (const float*)d_in[3];
  const float* dW2 = (const float*)d_in[4];
  const float* dW3 = (const float*)d_in[5];
  const float* db0 = (const float*)d_in[6];
  const float* db1 = (const float*)d_in[7];
  const float* db2 = (const float*)d_in[8];
  const float* db3 = (const float*)d_in[9];
  const float* pw0 = (const float*)d_in[10];
  const float* pw1 = (const float*)d_in[11];
  const float* pw2 = (const float*)d_in[12];
  const float* uW0 = (const float*)d_in[13];
  const float* uW1 = (const float*)d_in[14];
  const float* uW2 = (const float*)d_in[15];
  const float* ub0 = (const float*)d_in[16];
  const float* ub1 = (const float*)d_in[17];
  const float* ub2 = (const float*)d_in[18];

  char* p = (char*)d_ws;
  auto alloc = [&](size_t nbytes) -> void* {
    void* q = (void*)p; p += (nbytes + 255) & ~(size_t)255; return q;
  };
  unsigned* bits = (unsigned*)alloc((size_t)4096 * 128 * 4);
  int* ell = (int*)alloc((size_t)4096 * ECAP * 4);
  int* cnt = (int*)alloc(4096 * 4);
  int* inv1 = (int*)alloc(4096 * 4);
  int* inv2 = (int*)alloc(2048 * 4);
  int* inv3 = (int*)alloc(1024 * 4);
  unsigned char* Rb = (unsigned char*)alloc((size_t)4096 * 2048);
  float* Pp = (float*)alloc((size_t)8 * 1024 * 1024);   // split-K partials
  unsigned short* A1h = (unsigned short*)alloc((size_t)2048 * 2048 * 2);
  unsigned short* A1T = (unsigned short*)alloc((size_t)2048 * 2048 * 2);
  unsigned short* A2h = (unsigned short*)alloc((size_t)1024 * 1024 * 2);
  unsigned short* A2l = (unsigned short*)alloc((size_t)1024 * 1024 * 2);
  unsigned short* A2Th = (unsigned short*)alloc((size_t)1024 * 1024 * 2);
  unsigned short* A2Tl = (unsigned short*)alloc((size_t)1024 * 1024 * 2);
  unsigned short* A3h = (unsigned short*)alloc((size_t)512 * 512 * 2);
  unsigned short* A3l = (unsigned short*)alloc((size_t)512 * 512 * 2);
  unsigned short* Lb2h = (unsigned short*)alloc((size_t)1024 * 2048 * 2);
  unsigned short* Rt2h = (unsigned short*)alloc((size_t)1024 * 2048 * 2);
  unsigned short* Lb3h = (unsigned short*)alloc((size_t)512 * 1024 * 2);
  unsigned short* Lb3l = (unsigned short*)alloc((size_t)512 * 1024 * 2);
  unsigned short* Rt3h = (unsigned short*)alloc((size_t)512 * 1024 * 2);
  unsigned short* Rt3l = (unsigned short*)alloc((size_t)512 * 1024 * 2);
  unsigned short* xinh = (unsigned short*)alloc((size_t)4096 * 512 * 2);
  unsigned short* xinl = (unsigned short*)alloc((size_t)4096 * 512 * 2);
  float* x0 = (float*)alloc((size_t)4096 * HID * 4);
  float* x1 = (float*)alloc((size_t)2048 * HID * 4);
  float* x2 = (float*)alloc((size_t)1024 * HID * 4);
  unsigned short* xu1h = (unsigned short*)alloc((size_t)4096 * HID * 2);
  unsigned short* xu1l = (unsigned short*)alloc((size_t)4096 * HID * 2);
  unsigned short* xu2h = (unsigned short*)alloc((size_t)2048 * HID * 2);
  unsigned short* xu2l = (unsigned short*)alloc((size_t)2048 * HID * 2);
  unsigned short* xu3h = (unsigned short*)alloc((size_t)1024 * HID * 2);
  unsigned short* xu3l = (unsigned short*)alloc((size_t)1024 * HID * 2);
  unsigned short* xph = (unsigned short*)alloc((size_t)2048 * HID * 2);
  unsigned short* xpl = (unsigned short*)alloc((size_t)2048 * HID * 2);
  unsigned short* W0th = (unsigned short*)alloc((size_t)256 * 512 * 2);
  unsigned short* W0tl = (unsigned short*)alloc((size_t)256 * 512 * 2);
  unsigned short* W5th = (unsigned short*)alloc((size_t)5 * 256 * 256 * 2);
  unsigned short* W5tl = (unsigned short*)alloc((size_t)5 * 256 * 256 * 2);
  unsigned short* W2th = (unsigned short*)alloc((size_t)64 * 256 * 2);
  unsigned short* W2tl = (unsigned short*)alloc((size_t)64 * 256 * 2);
  float* Zs  = (float*)alloc((size_t)4096 * HID * 4);
  unsigned short* ZsTh = (unsigned short*)alloc((size_t)256 * 2048 * 2);
  unsigned short* ZsTl = (unsigned short*)alloc((size_t)256 * 2048 * 2);
  float* dinv0 = (float*)alloc(4096 * 4);
  float* dinv1 = (float*)alloc(2048 * 4);
  float* dinv2 = (float*)alloc(1024 * 4);
  float* dinv3 = (float*)alloc(512 * 4);
  float* score = (float*)alloc(4096 * 4);
  int* perm1 = (int*)alloc(2048 * 4);
  int* perm2 = (int*)alloc(1024 * 4);
  int* perm3 = (int*)alloc(512 * 4);
  if ((size_t)(p - (char*)d_ws) > ws_size) return;

  // 1: prep (bits zero + x split + all weight tsplits)
  k_prep<<<2640, 256, 0, stream>>>(x_in, dW0, dW1, dW2, dW3, uW0, uW1, uW2, bits,
                                   xinh, xinl, W0th, W0tl, W5th, W5tl, W2th, W2tl);
  // 2-3: graph build
  k_build_bits<<<EE / 256, 256, 0, stream>>>(ei, bits);
  k_ell<<<4096, 128, 0, stream>>>(bits, ell, cnt, dinv0);

  // 4-5: conv0 (+ pool-1 score fused)
  { dim3 g(4, 64);
    k_mm<1,1,0,2><<<g, 256, 0, stream>>>(xinh, xinl, W0th, W0tl, 4096, HID, IN_DIM, IN_DIM,
                                         nullptr, Zs, nullptr, nullptr, dinv0); }
  k_spmm_ell<256,1,1><<<4096, 256, 0, stream>>>(ell, cnt, Zs, dinv0, db0, x0, pw0, score);

  // 6-9: pool 1 (4096 -> 2048)
  k_topk<<<4096, 256, 0, stream>>>(score, 4096, 2048, perm1, inv1);
  k_pool_build<<<10240, 256, 0, stream>>>(x0, score, perm1, inv1, ell, cnt,
                                          xph, xpl, Rb, xu1h, xu1l);
  k_sq1<<<2048, 256, 0, stream>>>(ell, cnt, perm1, Rb, A1h, dinv1);
  // 10-12: conv1 (g1 fused epi; g2 split-K z=4; red -> x1 + score2)
  { dim3 g(4, 32);
    k_mm<1,1,0,4><<<g, 256, 0, stream>>>(xph, xpl, W5th, W5tl, 2048, HID, HID, HID,
                                         nullptr, Zs, ZsTh, ZsTl, dinv1); }
  { dim3 g(4, 32, 4);
    k_mm<0,1,0,0><<<g, 256, 0, stream>>>(A1h, nullptr, ZsTh, ZsTl, 2048, HID, 2048, 512,
                                         Pp, nullptr, nullptr, nullptr, nullptr); }
  k_red<2,1><<<2048, 256, 0, stream>>>(Pp, 4, 2048, 256, dinv1, Zs, db1,
                                       x1, nullptr, nullptr, nullptr, 1, pw1, score, nullptr, nullptr);

  // 13-17: pool 2 (2048 -> 1024)
  k_topk<<<2048, 256, 0, stream>>>(score, 2048, 1024, perm2, inv2);
  { dim3 g(64, 64); k_tr_b<0><<<g, 256, 0, stream>>>(A1h, nullptr, A1T, nullptr, 2048, 2048); }
  k_grow2<0,0><<<2048, 256, 0, stream>>>(A1h, nullptr, A1T, nullptr, perm2,
                                         Lb2h, nullptr, Rt2h, nullptr, 2048, 1024);
  { dim3 g(16, 16, 2);
    k_mm<0,0,0,0><<<g, 256, 0, stream>>>(Lb2h, nullptr, Rt2h, nullptr, 1024, 1024, 2048, 1024,
                                         Pp, nullptr, nullptr, nullptr, nullptr); }
  k_red<3,0><<<1024, 256, 0, stream>>>(Pp, 2, 1024, 1024, nullptr, nullptr, nullptr,
                                       nullptr, A2h, A2l, dinv2, 0, nullptr, nullptr, nullptr, nullptr);
  k_pool_fill<<<3072, 256, 0, stream>>>(x1, score, perm2, inv2, 1024, xph, xpl, xu2h, xu2l);
  // 18-20: conv2
  { dim3 g(4, 16);
    k_mm<1,1,0,4><<<g, 256, 0, stream>>>(xph, xpl, W5th + 65536, W5tl + 65536, 1024, HID, HID, HID,
                                         nullptr, Zs, ZsTh, ZsTl, dinv2); }
  { dim3 g(4, 16, 4);
    k_mm<1,1,0,0><<<g, 256, 0, stream>>>(A2h, A2l, ZsTh, ZsTl, 1024, HID, 1024, 256,
                                         Pp, nullptr, nullptr, nullptr, nullptr); }
  k_red<2,1><<<1024, 256, 0, stream>>>(Pp, 4, 1024, 256, dinv2, Zs, db2,
                                       x2, nullptr, nullptr, nullptr, 1, pw2, score, nullptr, nullptr);

  // 21-26: pool 3 (1024 -> 512)
  k_topk<<<1024, 256, 0, stream>>>(score, 1024, 512, perm3, inv3);
  { dim3 g(32, 32); k_tr_b<1><<<g, 256, 0, stream>>>(A2h, A2l, A2Th, A2Tl, 1024, 1024); }
  k_grow2<1,1><<<1024, 256, 0, stream>>>(A2h, A2l, A2Th, A2Tl, perm3,
                                         Lb3h, Lb3l, Rt3h, Rt3l, 1024, 512);
  { dim3 g(8, 8, 4);
    k_mm<1,1,1,0><<<g, 256, 0, stream>>>(Lb3h, Lb3l, Rt3h, Rt3l, 512, 512, 1024, 256,
                                         Pp, nullptr, nullptr, nullptr, nullptr); }
  k_red<3,0><<<512, 256, 0, stream>>>(Pp, 4, 512, 512, nullptr, nullptr, nullptr,
                                      nullptr, A3h, A3l, dinv3, 0, nullptr, nullptr, nullptr, nullptr);
  k_pool_fill<<<1536, 256, 0, stream>>>(x2, score, perm3, inv3, 512, xph, xpl, xu3h, xu3l);
  // 27-29: conv3 -> scatter into xu3 (x2 + relu(gcn3) at perm3 rows)
  { dim3 g(4, 8);
    k_mm<1,1,0,4><<<g, 256, 0, stream>>>(xph, xpl, W5th + 2 * 65536, W5tl + 2 * 65536, 512, HID, HID, HID,
                                         nullptr, Zs, ZsTh, ZsTl, dinv3); }
  { dim3 g(4, 8, 4);
    k_mm<1,1,0,0><<<g, 256, 0, stream>>>(A3h, A3l, ZsTh, ZsTl, 512, HID, 512, 128,
                                         Pp, nullptr, nullptr, nullptr, nullptr); }
  k_red<4,0><<<512, 256, 0, stream>>>(Pp, 4, 512, 256, dinv3, Zs, db3,
                                      nullptr, xu3h, xu3l, nullptr, 1, nullptr, nullptr, x2, perm3);

  // 30-32: up0 -> scatter into xu2
  { dim3 g(4, 16);
    k_mm<1,1,0,4><<<g, 256, 0, stream>>>(xu3h, xu3l, W5th + 3 * 65536, W5tl + 3 * 65536, 1024, HID, HID, HID,
                                         nullptr, Zs, ZsTh, ZsTl, dinv2); }
  { dim3 g(4, 16, 4);
    k_mm<1,1,0,0><<<g, 256, 0, stream>>>(A2h, A2l, ZsTh, ZsTl, 1024, HID, 1024, 256,
                                         Pp, nullptr, nullptr, nullptr, nullptr); }
  k_red<4,0><<<1024, 256, 0, stream>>>(Pp, 4, 1024, 256, dinv2, Zs, ub0,
                                       nullptr, xu2h, xu2l, nullptr, 1, nullptr, nullptr, x1, perm2);

  // 33-35: up1 -> scatter into xu1
  { dim3 g(4, 32);
    k_mm<1,1,0,4><<<g, 256, 0, stream>>>(xu2h, xu2l, W5th + 4 * 65536, W5tl + 4 * 65536, 2048, HID, HID, HID,
                                         nullptr, Zs, ZsTh, ZsTl, dinv1); }
  { dim3 g(4, 32, 4);
    k_mm<0,1,0,0><<<g, 256, 0, stream>>>(A1h, nullptr, ZsTh, ZsTl, 2048, HID, 2048, 512,
                                         Pp, nullptr, nullptr, nullptr, nullptr); }
  k_red<4,0><<<2048, 256, 0, stream>>>(Pp, 4, 2048, 256, dinv1, Zs, ub1,
                                       nullptr, xu1h, xu1l, nullptr, 1, nullptr, nullptr, x0, perm1);

  // 36-37: up2 (A0 sparse, Cout=64, no relu)
  { dim3 g(1, 64);
    k_mm<1,1,0,2><<<g, 256, 0, stream>>>(xu1h, xu1l, W2th, W2tl, 4096, OUT_DIM, HID, HID,
                                         nullptr, Zs, nullptr, nullptr, dinv0); }
  k_spmm_ell<64,0,0><<<4096, 256, 0, stream>>>(ell, cnt, Zs, dinv0, ub2, (float*)d_out, nullptr, nullptr);
}

// Round 8
// 232.461 us; speedup vs baseline: 1.3652x; 1.0486x over previous
//
#include <hip/hip_runtime.h>
#include <math.h>

#define NN 4096
#define EE 131072
#define IN_DIM 512
#define HID 256
#define OUT_DIM 64
#define ECAP 128

typedef __attribute__((ext_vector_type(8))) short bf8_t;
typedef __attribute__((ext_vector_type(4))) float f4_t;
typedef __attribute__((ext_vector_type(8))) unsigned short us8_t;
typedef __attribute__((ext_vector_type(4))) unsigned short us4_t;

#define GAS __attribute__((address_space(1)))
#define LAS __attribute__((address_space(3)))

// ---------------- bf16 helpers (RNE) ----------------
__device__ __forceinline__ unsigned short f2bf(float v){
  union { float f; unsigned u; } x; x.f = v;
  unsigned r = x.u + 0x7fffu + ((x.u >> 16) & 1u);
  return (unsigned short)(r >> 16);
}
__device__ __forceinline__ float bf2f(unsigned short h){
  union { float f; unsigned u; } x; x.u = ((unsigned)h) << 16;
  return x.f;
}

__device__ __forceinline__ float waveReduceSum(float v){
#pragma unroll
  for (int off = 32; off > 0; off >>= 1) v += __shfl_down(v, off);
  return v;
}

// ---------------- mega-prep: zero bits + split x_in + transpose-split all weights ----------------
__global__ __launch_bounds__(256) void k_prep(
    const float* __restrict__ x_in, const float* __restrict__ dW0,
    const float* __restrict__ dW1, const float* __restrict__ dW2,
    const float* __restrict__ dW3, const float* __restrict__ uW0,
    const float* __restrict__ uW1, const float* __restrict__ uW2,
    unsigned* __restrict__ bits,
    unsigned short* __restrict__ xinh, unsigned short* __restrict__ xinl,
    unsigned short* __restrict__ W0th, unsigned short* __restrict__ W0tl,
    unsigned short* __restrict__ W5th, unsigned short* __restrict__ W5tl,
    unsigned short* __restrict__ W2th, unsigned short* __restrict__ W2tl)
{
  int b = blockIdx.x;
  if (b < 128){                       // zero 2MB bit-adjacency
    int base = b * 4096 + threadIdx.x;
#pragma unroll
    for (int i = 0; i < 16; ++i) bits[base + i * 256] = 0;
    return;
  }
  b -= 128;
  if (b < 2048){                      // split x_in (4096x512 fp32 -> bf16 hi/lo)
    int i0 = b * 1024 + threadIdx.x;
#pragma unroll
    for (int i = 0; i < 4; ++i){
      int idx = i0 + i * 256;
      float v = x_in[idx];
      unsigned short h = f2bf(v);
      xinh[idx] = h; xinl[idx] = f2bf(v - bf2f(h));
    }
    return;
  }
  b -= 2048;
  const float* X; unsigned short *Th, *Tl; int R, C, tile;
  if (b < 128){ X = dW0; Th = W0th; Tl = W0tl; R = 512; C = 256; tile = b; }
  else if (b < 448){
    int t2 = b - 128; int z = t2 >> 6; int rem = t2 & 63;
    const float* ws[5] = {dW1, dW2, dW3, uW0, uW1};
    X = ws[z]; Th = W5th + (size_t)z * 65536; Tl = W5tl + (size_t)z * 65536;
    R = 256; C = 256; tile = rem;
  } else { X = uW2; Th = W2th; Tl = W2tl; R = 256; C = 64; tile = b - 448; }
  int tpr = C >> 5;
  int bx = (tile % tpr) * 32, by = (tile / tpr) * 32;
  __shared__ float t[32][33];
  int tx = threadIdx.x & 31, ty = threadIdx.x >> 5;
#pragma unroll
  for (int i = 0; i < 4; ++i)
    t[ty + i * 8][tx] = X[(size_t)(by + ty + i * 8) * C + bx + tx];
  __syncthreads();
#pragma unroll
  for (int i = 0; i < 4; ++i){
    float v = t[tx][ty + i * 8];
    unsigned short h = f2bf(v);
    size_t o = (size_t)(bx + ty + i * 8) * R + by + tx;
    Th[o] = h; Tl[o] = f2bf(v - bf2f(h));
  }
}

// ---------------- graph build: bitmask + ELL ----------------
__global__ void k_build_bits(const int* __restrict__ ei, unsigned* __restrict__ bits){
  int e = blockIdx.x * blockDim.x + threadIdx.x;
  if (e < EE){
    int r = ei[e], c = ei[EE + e];
    atomicOr(&bits[r * 128 + (c >> 5)], 1u << (c & 31));
  }
}

__global__ __launch_bounds__(128) void k_ell(const unsigned* __restrict__ bits,
                                             int* __restrict__ ell, int* __restrict__ cnt,
                                             float* __restrict__ dinv){
  int r = blockIdx.x, t = threadIdx.x;
  unsigned w = bits[r * 128 + t];
  int c = __popc(w);
  __shared__ int sc[128];
  sc[t] = c; __syncthreads();
  for (int off = 1; off < 128; off <<= 1){
    int a = sc[t], b = (t >= off) ? sc[t - off] : 0;
    __syncthreads(); sc[t] = a + b; __syncthreads();
  }
  int total = sc[127];
  int pos = sc[t] - c;
  int base = r * ECAP;
  while (w){
    int b = __ffs(w) - 1; w &= w - 1;
    if (pos < ECAP) ell[base + pos] = t * 32 + b;
    pos++;
  }
  if (t == 0){
    cnt[r] = (total < ECAP) ? total : ECAP;
    dinv[r] = 1.0f / sqrtf((float)total + 2.0f);
  }
}

// ---------------- fused SpMM (ELL, values==1) + GCN epilogue (+ optional score) ----------------
template<int NCOLS, int RELU, int SC>
__global__ __launch_bounds__(256) void k_spmm_ell(
    const int* __restrict__ ell, const int* __restrict__ cnt,
    const float* __restrict__ Zs, const float* __restrict__ dinv,
    const float* __restrict__ bias, float* __restrict__ out,
    const float* __restrict__ scw, float* __restrict__ score)
{
  int r = blockIdx.x;
  __shared__ int s_idx[ECAP];
  __shared__ int s_n;
  __shared__ float sh[4 * NCOLS];
  __shared__ float sd[4], sq[4];
  if (threadIdx.x == 0) s_n = cnt[r];
  for (int i = threadIdx.x; i < ECAP; i += 256) s_idx[i] = ell[r * ECAP + i];
  __syncthreads();
  int n = s_n; if (n > ECAP) n = ECAP;
  int wv = threadIdx.x >> 6, lane = threadIdx.x & 63;
  if (NCOLS == 256){
    f4_t acc = (f4_t){0.f, 0.f, 0.f, 0.f};
    for (int e = wv; e < n; e += 4){
      const f4_t* row = (const f4_t*)(Zs + (size_t)s_idx[e] * 256);
      acc += row[lane];
    }
    ((f4_t*)(sh + wv * 256))[lane] = acc;
  } else {
    float acc = 0.f;
    for (int e = wv; e < n; e += 4)
      acc += Zs[(size_t)s_idx[e] * 64 + lane];
    sh[wv * 64 + lane] = acc;
  }
  __syncthreads();
  int t = threadIdx.x;
  float o = 0.f;
  if (t < NCOLS){
    float y = sh[t] + sh[NCOLS + t] + sh[2 * NCOLS + t] + sh[3 * NCOLS + t];
    float z = Zs[(size_t)r * NCOLS + t];
    o = dinv[r] * (y + 2.0f * z) + bias[t];
    if (RELU) o = fmaxf(o, 0.f);
    out[(size_t)r * NCOLS + t] = o;
  }
  if (SC){
    float w = scw[t];
    float d = waveReduceSum(o * w);
    float q = waveReduceSum(w * w);
    if (!lane){ sd[wv] = d; sq[wv] = q; }
    __syncthreads();
    if (!t) score[r] = tanhf((sd[0] + sd[1] + sd[2] + sd[3]) / sqrtf(sq[0] + sq[1] + sq[2] + sq[3]));
  }
}

// ---------------- pool1: pool_x2 + build_Rb + xu1 non-selected fill (one dispatch) ----------------
__global__ __launch_bounds__(256) void k_pool_build(
    const float* __restrict__ x0, const float* __restrict__ score,
    const int* __restrict__ perm1, const int* __restrict__ inv1,
    const int* __restrict__ ell, const int* __restrict__ cnt,
    unsigned short* __restrict__ xph, unsigned short* __restrict__ xpl,
    unsigned char* __restrict__ Rb,
    unsigned short* __restrict__ xu1h, unsigned short* __restrict__ xu1l)
{
  int b = blockIdx.x;
  if (b < 2048){                           // gated pooled features
    int pr = perm1[b]; float s = score[pr];
    int c = threadIdx.x;
    float v = x0[(size_t)pr * 256 + c] * s;
    unsigned short h = f2bf(v);
    xph[(size_t)b * 256 + c] = h;
    xpl[(size_t)b * 256 + c] = f2bf(v - bf2f(h));
    return;
  }
  if (b < 6144){                           // Rb[k][s] = (A0+I)[k][perm1[s]] u8
    int k = b - 2048;
    __shared__ unsigned char row[2048];
    for (int i = threadIdx.x; i < 512; i += 256) ((int*)row)[i] = 0;
    __syncthreads();
    int n = cnt[k];
    for (int e = threadIdx.x; e < n; e += 256){
      int s = inv1[ell[k * ECAP + e]];
      if (s >= 0) row[s] = 1;
    }
    __syncthreads();
    if (threadIdx.x == 0){
      int sk = inv1[k];
      if (sk >= 0) row[sk] += 1;
    }
    __syncthreads();
    *(uint2*)(Rb + (size_t)k * 2048 + threadIdx.x * 8) = *(uint2*)(row + threadIdx.x * 8);
    return;
  }
  int r = b - 6144;                        // xu1 fill: non-selected rows = x0
  if (inv1[r] < 0){
    int c = threadIdx.x;
    float v = x0[(size_t)r * 256 + c];
    unsigned short h = f2bf(v);
    xu1h[(size_t)r * 256 + c] = h;
    xu1l[(size_t)r * 256 + c] = f2bf(v - bf2f(h));
  }
}

// ---------------- pool2/3 prep: pooled-x + xu fill + L row-gather(+I) + transpose-gather(+I) ----------------
// Block ranges: [0,k) pool | [k,k+n) fill | [k+n,2k+n) L rows | rest: (n/32)^2 transpose tiles
template<int SRCL, int OUTL>
__global__ __launch_bounds__(256) void k_pp(
    const float* __restrict__ x, const float* __restrict__ score,
    const int* __restrict__ perm, const int* __restrict__ inv, int n, int k,
    unsigned short* __restrict__ xph, unsigned short* __restrict__ xpl,
    unsigned short* __restrict__ xuh, unsigned short* __restrict__ xul,
    const unsigned short* __restrict__ Ah, const unsigned short* __restrict__ Al,
    unsigned short* __restrict__ Lh, unsigned short* __restrict__ Ll,
    unsigned short* __restrict__ Rh, unsigned short* __restrict__ Rl)
{
  __shared__ float t[32][33];
  __shared__ int sinv[32];
  int b = blockIdx.x, c = threadIdx.x;
  if (b < k){                              // pooled gated features
    int pr = perm[b]; float s = score[pr];
    float v = x[(size_t)pr * 256 + c] * s;
    unsigned short h = f2bf(v);
    xph[(size_t)b * 256 + c] = h;
    xpl[(size_t)b * 256 + c] = f2bf(v - bf2f(h));
    return;
  }
  b -= k;
  if (b < n){                              // xu fill: non-selected rows
    if (inv[b] < 0){
      float v = x[(size_t)b * 256 + c];
      unsigned short h = f2bf(v);
      xuh[(size_t)b * 256 + c] = h;
      xul[(size_t)b * 256 + c] = f2bf(v - bf2f(h));
    }
    return;
  }
  b -= n;
  if (b < k){                              // L[r][:] = A[perm r][:] + I
    int r = b, pr = perm[r];
    for (int cc = threadIdx.x; cc < n; cc += 256){
      float v = bf2f(Ah[(size_t)pr * n + cc]);
      if (SRCL) v += bf2f(Al[(size_t)pr * n + cc]);
      if (pr == cc) v += 1.f;
      unsigned short h = f2bf(v);
      Lh[(size_t)r * n + cc] = h;
      if (OUTL) Ll[(size_t)r * n + cc] = f2bf(v - bf2f(h));
    }
    return;
  }
  b -= k;
  // transpose-gather: R[s][kk] = A[kk][perm s] + (kk==perm s), only selected cols
  int tpr = n >> 5;
  int kt = b / tpr, ct = b - kt * tpr;
  int tx = threadIdx.x & 31, ty = threadIdx.x >> 5;
  if (threadIdx.x < 32) sinv[threadIdx.x] = inv[ct * 32 + threadIdx.x];
#pragma unroll
  for (int i = 0; i < 4; ++i){
    int kl = ty + i * 8;
    size_t src = (size_t)(kt * 32 + kl) * n + ct * 32 + tx;
    float v = bf2f(Ah[src]);
    if (SRCL) v += bf2f(Al[src]);
    t[kl][tx] = v;
  }
  __syncthreads();
#pragma unroll
  for (int i = 0; i < 4; ++i){
    int cl = ty + i * 8;
    int s = sinv[cl];
    if (s >= 0){
      float v = t[tx][cl];
      if (kt * 32 + tx == ct * 32 + cl) v += 1.f;
      unsigned short h = f2bf(v);
      size_t o = (size_t)s * n + kt * 32 + tx;
      Rh[o] = h;
      if (OUTL) Rl[o] = f2bf(v - bf2f(h));
    }
  }
}

// ---------------- pool-1 squaring from ELL (u8 Rb) ----------------
__global__ __launch_bounds__(256) void k_sq1(const int* __restrict__ ell, const int* __restrict__ cnt,
                                             const int* __restrict__ perm,
                                             const unsigned char* __restrict__ Rb,
                                             unsigned short* __restrict__ A1h,
                                             float* __restrict__ dinv1){
  int r = blockIdx.x;
  int pr = perm[r];
  __shared__ int s_idx[ECAP];
  __shared__ int s_n;
  __shared__ float sred[4];
  if (threadIdx.x == 0) s_n = cnt[pr];
  for (int i = threadIdx.x; i < ECAP; i += 256) s_idx[i] = ell[pr * ECAP + i];
  __syncthreads();
  int n = s_n; if (n > ECAP) n = ECAP;
  int colb = threadIdx.x * 8;
  uint2 acc = *(const uint2*)(Rb + (size_t)pr * 2048 + colb);
  for (int e = 0; e < n; ++e){
    uint2 v = *(const uint2*)(Rb + (size_t)s_idx[e] * 2048 + colb);
    acc.x += v.x; acc.y += v.y;   // bytewise, no carries (values <=130)
  }
  float fs = 0.f;
  us8_t o;
#pragma unroll
  for (int j = 0; j < 8; ++j){
    unsigned byte = ((j < 4 ? acc.x : acc.y) >> (8 * (j & 3))) & 0xFFu;
    if (colb + j == r) byte = 0;
    float f = (float)byte;
    fs += f;
    o[j] = f2bf(f);
  }
  *(us8_t*)(A1h + (size_t)r * 2048 + colb) = o;
  fs = waveReduceSum(fs);
  int lane = threadIdx.x & 63, wd = threadIdx.x >> 6;
  if (!lane) sred[wd] = fs;
  __syncthreads();
  if (!threadIdx.x)
    dinv1[r] = 1.0f / sqrtf(sred[0] + sred[1] + sred[2] + sred[3] + 2.0f);
}

// ---------------- MFMA GEMM: global_load_lds double-buffered ----------------
// EPI 0: write fp32 partial P[z][M][N] (split-K)
// EPI 2: Cf = dinv[row]*acc
// EPI 4: sv = dinv[row]*acc; Cf = sv; Ch/Cl[col*M+row] = split(sv)  (transposed split)
template<int HAS_AL, int HAS_BL, int HAS_LL, int EPI>
__global__ __launch_bounds__(256) void k_mm(
    const unsigned short* __restrict__ Ah, const unsigned short* __restrict__ Al,
    const unsigned short* __restrict__ Bh, const unsigned short* __restrict__ Bl,
    int M, int N, int K, int KS, float* __restrict__ P,
    float* __restrict__ Cf, unsigned short* __restrict__ Ch, unsigned short* __restrict__ Cl,
    const float* __restrict__ dinv)
{
  constexpr int NARR = 2 + HAS_AL + HAS_BL;
  constexpr int BUF = NARR * 8192;
  __shared__ int4 ldsq[NARR * 512 * 2];
  char* ldsc = (char*)ldsq;

  const int tid = threadIdx.x, lane = tid & 63, wid = tid >> 6;
  const int wm = wid >> 1, wn = wid & 1;
  const int bm = blockIdx.y << 6, bn = blockIdx.x << 6;
  const int z = blockIdx.z;
  const int l15 = lane & 15, l4 = lane >> 4;

  f4_t acc[2][2];
#pragma unroll
  for (int i = 0; i < 2; ++i)
#pragma unroll
    for (int j = 0; j < 2; ++j) acc[i][j] = (f4_t){0.f, 0.f, 0.f, 0.f};

  const size_t rb = (size_t)K * 2;
  const size_t kz = (size_t)z * KS * 2;
  const char* pAh = (const char*)Ah + (size_t)bm * rb;
  const char* pAl = HAS_AL ? (const char*)Al + (size_t)bm * rb : nullptr;
  const char* pBh = (const char*)Bh + (size_t)bn * rb;
  const char* pBl = HAS_BL ? (const char*)Bl + (size_t)bn * rb : nullptr;

  auto stage = [&](int t, int b2){
    char* ldsb = ldsc + b2 * BUF;
    const size_t kb = kz + (size_t)t * 128;
#pragma unroll
    for (int it = 0; it < 2; ++it){
      const int idx = tid + (it << 8);
      const int row = idx >> 3;
      const int kc = ((idx & 7) << 4) ^ ((row & 7) << 4);  // pre-swizzled source col
      const size_t go = (size_t)row * rb + kb + kc;
      const int lo = idx * 16;
      __builtin_amdgcn_global_load_lds((const GAS void*)(pAh + go), (LAS void*)(ldsb + lo), 16, 0, 0);
      __builtin_amdgcn_global_load_lds((const GAS void*)(pBh + go), (LAS void*)(ldsb + 8192 + lo), 16, 0, 0);
      if (HAS_AL)
        __builtin_amdgcn_global_load_lds((const GAS void*)(pAl + go), (LAS void*)(ldsb + 16384 + lo), 16, 0, 0);
      if (HAS_BL)
        __builtin_amdgcn_global_load_lds((const GAS void*)(pBl + go), (LAS void*)(ldsb + (2 + HAS_AL) * 8192 + lo), 16, 0, 0);
    }
  };

  const int T = KS >> 6;
  stage(0, 0);
  int b = 0;
  for (int t = 0; t < T; ++t){
    if (t + 1 < T){
      stage(t + 1, b ^ 1);
      if constexpr (NARR == 2) asm volatile("s_waitcnt vmcnt(4)" ::: "memory");
      else if constexpr (NARR == 3) asm volatile("s_waitcnt vmcnt(6)" ::: "memory");
      else asm volatile("s_waitcnt vmcnt(8)" ::: "memory");
    } else {
      asm volatile("s_waitcnt vmcnt(0)" ::: "memory");
    }
    __syncthreads();
    const char* ldsb = ldsc + b * BUF;
#pragma unroll
    for (int ks = 0; ks < 2; ++ks){
      bf8_t aH[2], aL[2], bH[2], bL[2];
#pragma unroll
      for (int f = 0; f < 2; ++f){
        int ar = wm * 32 + f * 16 + l15;
        int aoff = ar * 128 + (((ks * 64) + (l4 << 4)) ^ ((ar & 7) << 4));
        aH[f] = *(const bf8_t*)(ldsb + aoff);
        if (HAS_AL) aL[f] = *(const bf8_t*)(ldsb + 16384 + aoff);
        int br = wn * 32 + f * 16 + l15;
        int boff = br * 128 + (((ks * 64) + (l4 << 4)) ^ ((br & 7) << 4));
        bH[f] = *(const bf8_t*)(ldsb + 8192 + boff);
        if (HAS_BL) bL[f] = *(const bf8_t*)(ldsb + (2 + HAS_AL) * 8192 + boff);
      }
#pragma unroll
      for (int i = 0; i < 2; ++i)
#pragma unroll
        for (int j = 0; j < 2; ++j){
          acc[i][j] = __builtin_amdgcn_mfma_f32_16x16x32_bf16(aH[i], bH[j], acc[i][j], 0, 0, 0);
          if (HAS_BL) acc[i][j] = __builtin_amdgcn_mfma_f32_16x16x32_bf16(aH[i], bL[j], acc[i][j], 0, 0, 0);
          if (HAS_AL) acc[i][j] = __builtin_amdgcn_mfma_f32_16x16x32_bf16(aL[i], bH[j], acc[i][j], 0, 0, 0);
          if (HAS_LL) acc[i][j] = __builtin_amdgcn_mfma_f32_16x16x32_bf16(aL[i], bL[j], acc[i][j], 0, 0, 0);
        }
    }
    __syncthreads();
    b ^= 1;
  }

  float* Pz = (EPI == 0) ? P + (size_t)z * M * N : nullptr;
#pragma unroll
  for (int i = 0; i < 2; ++i)
#pragma unroll
    for (int j = 0; j < 2; ++j)
#pragma unroll
      for (int r = 0; r < 4; ++r){
        int grow = bm + wm * 32 + i * 16 + l4 * 4 + r;
        int gcol = bn + wn * 32 + j * 16 + l15;
        float v = acc[i][j][r];
        size_t o = (size_t)grow * N + gcol;
        if (EPI == 0){
          Pz[o] = v;
        } else if (EPI == 2){
          Cf[o] = dinv[grow] * v;
        } else { // EPI == 4
          float sv = dinv[grow] * v;
          Cf[o] = sv;
          unsigned short h = f2bf(sv);
          size_t ot = (size_t)gcol * M + grow;
          Ch[ot] = h; Cl[ot] = f2bf(sv - bf2f(h));
        }
      }
}

// ---------------- split-K reduce, wave-per-row, float4 (4 rows per block) ----------------
// EPI 2: Of = relu?(dinv[row]*(s+2Zs)+bias); optional score (SC, NC==256)
// EPI 3: v = (c==row)?0:s; Oh/Ol = split(v); dout[row] = 1/sqrt(rowsum+2)
// EPI 4: out = relu?(dinv[row]*(s+2Zs)+bias); comb = res[perm[row]]+out; Oh/Ol[perm[row]*NC+c] = split(comb)
template<int EPI, int SC>
__global__ __launch_bounds__(256) void k_red(
    const float* __restrict__ P, int Z, int M, int NC,
    const float* __restrict__ dinv, const float* __restrict__ Zs,
    const float* __restrict__ bias,
    float* __restrict__ Of, unsigned short* __restrict__ Oh, unsigned short* __restrict__ Ol,
    float* __restrict__ dout, int relu,
    const float* __restrict__ scw, float* __restrict__ score,
    const float* __restrict__ res, const int* __restrict__ permsel)
{
  int w = threadIdx.x >> 6, lane = threadIdx.x & 63;
  int row = blockIdx.x * 4 + w;
  int prow = (EPI == 4) ? permsel[row] : 0;
  float di = (EPI != 3) ? dinv[row] : 0.f;
  float rsum = 0.f, o_d = 0.f, o_q = 0.f;
  for (int c0 = lane * 4; c0 < NC; c0 += 256){
    size_t o = (size_t)row * NC + c0;
    f4_t s = *(const f4_t*)(P + o);
    for (int zz = 1; zz < Z; ++zz) s += *(const f4_t*)(P + (size_t)zz * M * NC + o);
    if (EPI == 2){
      f4_t z4 = *(const f4_t*)(Zs + o);
      f4_t b4 = *(const f4_t*)(bias + c0);
      f4_t out;
#pragma unroll
      for (int j = 0; j < 4; ++j){
        float v = di * (s[j] + 2.0f * z4[j]) + b4[j];
        if (relu) v = fmaxf(v, 0.f);
        out[j] = v;
      }
      *(f4_t*)(Of + o) = out;
      if (SC){
        f4_t w4 = *(const f4_t*)(scw + c0);
#pragma unroll
        for (int j = 0; j < 4; ++j){ o_d += out[j] * w4[j]; o_q += w4[j] * w4[j]; }
      }
    } else if (EPI == 3){
      us4_t h4, l4v;
#pragma unroll
      for (int j = 0; j < 4; ++j){
        float v = (c0 + j == row) ? 0.f : s[j];
        unsigned short h = f2bf(v);
        h4[j] = h; l4v[j] = f2bf(v - bf2f(h));
        rsum += v;
      }
      *(us4_t*)(Oh + o) = h4;
      *(us4_t*)(Ol + o) = l4v;
    } else { // EPI == 4
      f4_t z4 = *(const f4_t*)(Zs + o);
      f4_t b4 = *(const f4_t*)(bias + c0);
      f4_t r4 = *(const f4_t*)(res + (size_t)prow * NC + c0);
      us4_t h4, l4v;
#pragma unroll
      for (int j = 0; j < 4; ++j){
        float v = di * (s[j] + 2.0f * z4[j]) + b4[j];
        if (relu) v = fmaxf(v, 0.f);
        float comb = r4[j] + v;
        unsigned short h = f2bf(comb);
        h4[j] = h; l4v[j] = f2bf(comb - bf2f(h));
      }
      size_t od = (size_t)prow * NC + c0;
      *(us4_t*)(Oh + od) = h4;
      *(us4_t*)(Ol + od) = l4v;
    }
  }
  if (EPI == 3){
    rsum = waveReduceSum(rsum);
    if (!lane) dout[row] = 1.0f / sqrtf(rsum + 2.0f);
  }
  if (SC){
    o_d = waveReduceSum(o_d);
    o_q = waveReduceSum(o_q);
    if (!lane) score[row] = tanhf(o_d / sqrtf(o_q));
  }
}

// ---------------- topk (stable descending rank) ----------------
__global__ void k_topk(const float* __restrict__ score, int n, int k,
                       int* __restrict__ perm, int* __restrict__ inv){
  int i = blockIdx.x; float si = score[i];
  int cnt = 0;
  for (int j = threadIdx.x; j < n; j += 256){
    float sj = score[j];
    if (sj > si || (sj == si && j < i)) cnt++;
  }
#pragma unroll
  for (int off = 32; off > 0; off >>= 1) cnt += __shfl_down(cnt, off);
  __shared__ int sh[4];
  int lane = threadIdx.x & 63, wid = threadIdx.x >> 6;
  if (lane == 0) sh[wid] = cnt;
  __syncthreads();
  if (threadIdx.x == 0){
    int rank = sh[0] + sh[1] + sh[2] + sh[3];
    if (rank < k){ perm[rank] = i; inv[i] = rank; }
    else inv[i] = -1;
  }
}

// ---------------- host orchestration ----------------
extern "C" void kernel_launch(void* const* d_in, const int* in_sizes, int n_in,
                              void* d_out, int out_size, void* d_ws, size_t ws_size,
                              hipStream_t stream){
  (void)in_sizes; (void)n_in; (void)out_size;
  const float* x_in = (const float*)d_in[0];
  const int*   ei   = (const int*)d_in[1];
  const float* dW0 = (const float*)d_in[2];
  const float* dW1 = (const float*)d_in[3];
  const float* dW2 = (const float*)d_in[4];
  const float* dW3 = (const float*)d_in[5];
  const float* db0 = (const float*)d_in[6];
  const float* db1 = (const float*)d_in[7];
  const float* db2 = (const float*)d_in[8];
  const float* db3 = (const float*)d_in[9];
  const float* pw0 = (const float*)d_in[10];
  const float* pw1 = (const float*)d_in[11];
  const float* pw2 = (const float*)d_in[12];
  const float* uW0 = (const float*)d_in[13];
  const float* uW1 = (const float*)d_in[14];
  const float* uW2 = (const float*)d_in[15];
  const float* ub0 = (const float*)d_in[16];
  const float* ub1 = (const float*)d_in[17];
  const float* ub2 = (const float*)d_in[18];

  char* p = (char*)d_ws;
  auto alloc = [&](size_t nbytes) -> void* {
    void* q = (void*)p; p += (nbytes + 255) & ~(size_t)255; return q;
  };
  unsigned* bits = (unsigned*)alloc((size_t)4096 * 128 * 4);
  int* ell = (int*)alloc((size_t)4096 * ECAP * 4);
  int* cnt = (int*)alloc(4096 * 4);
  int* inv1 = (int*)alloc(4096 * 4);
  int* inv2 = (int*)alloc(2048 * 4);
  int* inv3 = (int*)alloc(1024 * 4);
  unsigned char* Rb = (unsigned char*)alloc((size_t)4096 * 2048);
  float* Pp = (float*)alloc((size_t)8 * 1024 * 1024);   // split-K partials
  unsigned short* A1h = (unsigned short*)alloc((size_t)2048 * 2048 * 2);
  unsigned short* A2h = (unsigned short*)alloc((size_t)1024 * 1024 * 2);
  unsigned short* A2l = (unsigned short*)alloc((size_t)1024 * 1024 * 2);
  unsigned short* A3h = (unsigned short*)alloc((size_t)512 * 512 * 2);
  unsigned short* A3l = (unsigned short*)alloc((size_t)512 * 512 * 2);
  unsigned short* Lb2h = (unsigned short*)alloc((size_t)1024 * 2048 * 2);
  unsigned short* Rt2h = (unsigned short*)alloc((size_t)1024 * 2048 * 2);
  unsigned short* Lb3h = (unsigned short*)alloc((size_t)512 * 1024 * 2);
  unsigned short* Lb3l = (unsigned short*)alloc((size_t)512 * 1024 * 2);
  unsigned short* Rt3h = (unsigned short*)alloc((size_t)512 * 1024 * 2);
  unsigned short* Rt3l = (unsigned short*)alloc((size_t)512 * 1024 * 2);
  unsigned short* xinh = (unsigned short*)alloc((size_t)4096 * 512 * 2);
  unsigned short* xinl = (unsigned short*)alloc((size_t)4096 * 512 * 2);
  float* x0 = (float*)alloc((size_t)4096 * HID * 4);
  float* x1 = (float*)alloc((size_t)2048 * HID * 4);
  float* x2 = (float*)alloc((size_t)1024 * HID * 4);
  unsigned short* xu1h = (unsigned short*)alloc((size_t)4096 * HID * 2);
  unsigned short* xu1l = (unsigned short*)alloc((size_t)4096 * HID * 2);
  unsigned short* xu2h = (unsigned short*)alloc((size_t)2048 * HID * 2);
  unsigned short* xu2l = (unsigned short*)alloc((size_t)2048 * HID * 2);
  unsigned short* xu3h = (unsigned short*)alloc((size_t)1024 * HID * 2);
  unsigned short* xu3l = (unsigned short*)alloc((size_t)1024 * HID * 2);
  unsigned short* xph = (unsigned short*)alloc((size_t)2048 * HID * 2);
  unsigned short* xpl = (unsigned short*)alloc((size_t)2048 * HID * 2);
  unsigned short* W0th = (unsigned short*)alloc((size_t)256 * 512 * 2);
  unsigned short* W0tl = (unsigned short*)alloc((size_t)256 * 512 * 2);
  unsigned short* W5th = (unsigned short*)alloc((size_t)5 * 256 * 256 * 2);
  unsigned short* W5tl = (unsigned short*)alloc((size_t)5 * 256 * 256 * 2);
  unsigned short* W2th = (unsigned short*)alloc((size_t)64 * 256 * 2);
  unsigned short* W2tl = (unsigned short*)alloc((size_t)64 * 256 * 2);
  float* Zs  = (float*)alloc((size_t)4096 * HID * 4);
  unsigned short* ZsTh = (unsigned short*)alloc((size_t)256 * 2048 * 2);
  unsigned short* ZsTl = (unsigned short*)alloc((size_t)256 * 2048 * 2);
  float* dinv0 = (float*)alloc(4096 * 4);
  float* dinv1 = (float*)alloc(2048 * 4);
  float* dinv2 = (float*)alloc(1024 * 4);
  float* dinv3 = (float*)alloc(512 * 4);
  float* score = (float*)alloc(4096 * 4);
  int* perm1 = (int*)alloc(2048 * 4);
  int* perm2 = (int*)alloc(1024 * 4);
  int* perm3 = (int*)alloc(512 * 4);
  if ((size_t)(p - (char*)d_ws) > ws_size) return;

  // 1: prep (bits zero + x split + all weight tsplits)
  k_prep<<<2640, 256, 0, stream>>>(x_in, dW0, dW1, dW2, dW3, uW0, uW1, uW2, bits,
                                   xinh, xinl, W0th, W0tl, W5th, W5tl, W2th, W2tl);
  // 2-3: graph build
  k_build_bits<<<EE / 256, 256, 0, stream>>>(ei, bits);
  k_ell<<<4096, 128, 0, stream>>>(bits, ell, cnt, dinv0);

  // 4-5: conv0 (+ pool-1 score fused)
  { dim3 g(4, 64);
    k_mm<1,1,0,2><<<g, 256, 0, stream>>>(xinh, xinl, W0th, W0tl, 4096, HID, IN_DIM, IN_DIM,
                                         nullptr, Zs, nullptr, nullptr, dinv0); }
  k_spmm_ell<256,1,1><<<4096, 256, 0, stream>>>(ell, cnt, Zs, dinv0, db0, x0, pw0, score);

  // 6-8: pool 1 (4096 -> 2048)
  k_topk<<<4096, 256, 0, stream>>>(score, 4096, 2048, perm1, inv1);
  k_pool_build<<<10240, 256, 0, stream>>>(x0, score, perm1, inv1, ell, cnt,
                                          xph, xpl, Rb, xu1h, xu1l);
  k_sq1<<<2048, 256, 0, stream>>>(ell, cnt, perm1, Rb, A1h, dinv1);
  // 9-11: conv1 (g1 fused epi; g2 split-K z=4; red -> x1 + score2)
  { dim3 g(4, 32);
    k_mm<1,1,0,4><<<g, 256, 0, stream>>>(xph, xpl, W5th, W5tl, 2048, HID, HID, HID,
                                         nullptr, Zs, ZsTh, ZsTl, dinv1); }
  { dim3 g(4, 32, 4);
    k_mm<0,1,0,0><<<g, 256, 0, stream>>>(A1h, nullptr, ZsTh, ZsTl, 2048, HID, 2048, 512,
                                         Pp, nullptr, nullptr, nullptr, nullptr); }
  k_red<2,1><<<512, 256, 0, stream>>>(Pp, 4, 2048, 256, dinv1, Zs, db1,
                                      x1, nullptr, nullptr, nullptr, 1, pw1, score, nullptr, nullptr);

  // 12-15: pool 2 (2048 -> 1024)
  k_topk<<<2048, 256, 0, stream>>>(score, 2048, 1024, perm2, inv2);
  k_pp<0,0><<<8192, 256, 0, stream>>>(x1, score, perm2, inv2, 2048, 1024,
                                      xph, xpl, xu2h, xu2l, A1h, nullptr,
                                      Lb2h, nullptr, Rt2h, nullptr);
  { dim3 g(16, 16, 2);
    k_mm<0,0,0,0><<<g, 256, 0, stream>>>(Lb2h, nullptr, Rt2h, nullptr, 1024, 1024, 2048, 1024,
                                         Pp, nullptr, nullptr, nullptr, nullptr); }
  k_red<3,0><<<256, 256, 0, stream>>>(Pp, 2, 1024, 1024, nullptr, nullptr, nullptr,
                                      nullptr, A2h, A2l, dinv2, 0, nullptr, nullptr, nullptr, nullptr);
  // 16-18: conv2
  { dim3 g(4, 16);
    k_mm<1,1,0,4><<<g, 256, 0, stream>>>(xph, xpl, W5th + 65536, W5tl + 65536, 1024, HID, HID, HID,
                                         nullptr, Zs, ZsTh, ZsTl, dinv2); }
  { dim3 g(4, 16, 4);
    k_mm<1,1,0,0><<<g, 256, 0, stream>>>(A2h, A2l, ZsTh, ZsTl, 1024, HID, 1024, 256,
                                         Pp, nullptr, nullptr, nullptr, nullptr); }
  k_red<2,1><<<256, 256, 0, stream>>>(Pp, 4, 1024, 256, dinv2, Zs, db2,
                                      x2, nullptr, nullptr, nullptr, 1, pw2, score, nullptr, nullptr);

  // 19-22: pool 3 (1024 -> 512)
  k_topk<<<1024, 256, 0, stream>>>(score, 1024, 512, perm3, inv3);
  k_pp<1,1><<<3072, 256, 0, stream>>>(x2, score, perm3, inv3, 1024, 512,
                                      xph, xpl, xu3h, xu3l, A2h, A2l,
                                      Lb3h, Lb3l, Rt3h, Rt3l);
  { dim3 g(8, 8, 4);
    k_mm<1,1,1,0><<<g, 256, 0, stream>>>(Lb3h, Lb3l, Rt3h, Rt3l, 512, 512, 1024, 256,
                                         Pp, nullptr, nullptr, nullptr, nullptr); }
  k_red<3,0><<<128, 256, 0, stream>>>(Pp, 4, 512, 512, nullptr, nullptr, nullptr,
                                      nullptr, A3h, A3l, dinv3, 0, nullptr, nullptr, nullptr, nullptr);
  // 23-25: conv3 -> scatter into xu3 (x2 + relu(gcn3) at perm3 rows)
  { dim3 g(4, 8);
    k_mm<1,1,0,4><<<g, 256, 0, stream>>>(xph, xpl, W5th + 2 * 65536, W5tl + 2 * 65536, 512, HID, HID, HID,
                                         nullptr, Zs, ZsTh, ZsTl, dinv3); }
  { dim3 g(4, 8, 4);
    k_mm<1,1,0,0><<<g, 256, 0, stream>>>(A3h, A3l, ZsTh, ZsTl, 512, HID, 512, 128,
                                         Pp, nullptr, nullptr, nullptr, nullptr); }
  k_red<4,0><<<128, 256, 0, stream>>>(Pp, 4, 512, 256, dinv3, Zs, db3,
                                      nullptr, xu3h, xu3l, nullptr, 1, nullptr, nullptr, x2, perm3);

  // 26-28: up0 -> scatter into xu2
  { dim3 g(4, 16);
    k_mm<1,1,0,4><<<g, 256, 0, stream>>>(xu3h, xu3l, W5th + 3 * 65536, W5tl + 3 * 65536, 1024, HID, HID, HID,
                                         nullptr, Zs, ZsTh, ZsTl, dinv2); }
  { dim3 g(4, 16, 4);
    k_mm<1,1,0,0><<<g, 256, 0, stream>>>(A2h, A2l, ZsTh, ZsTl, 1024, HID, 1024, 256,
                                         Pp, nullptr, nullptr, nullptr, nullptr); }
  k_red<4,0><<<256, 256, 0, stream>>>(Pp, 4, 1024, 256, dinv2, Zs, ub0,
                                      nullptr, xu2h, xu2l, nullptr, 1, nullptr, nullptr, x1, perm2);

  // 29-31: up1 -> scatter into xu1
  { dim3 g(4, 32);
    k_mm<1,1,0,4><<<g, 256, 0, stream>>>(xu2h, xu2l, W5th + 4 * 65536, W5tl + 4 * 65536, 2048, HID, HID, HID,
                                         nullptr, Zs, ZsTh, ZsTl, dinv1); }
  { dim3 g(4, 32, 4);
    k_mm<0,1,0,0><<<g, 256, 0, stream>>>(A1h, nullptr, ZsTh, ZsTl, 2048, HID, 2048, 512,
                                         Pp, nullptr, nullptr, nullptr, nullptr); }
  k_red<4,0><<<512, 256, 0, stream>>>(Pp, 4, 2048, 256, dinv1, Zs, ub1,
                                      nullptr, xu1h, xu1l, nullptr, 1, nullptr, nullptr, x0, perm1);

  // 32-33: up2 (A0 sparse, Cout=64, no relu)
  { dim3 g(1, 64);
    k_mm<1,1,0,2><<<g, 256, 0, stream>>>(xu1h, xu1l, W2th, W2tl, 4096, OUT_DIM, HID, HID,
                                         nullptr, Zs, nullptr, nullptr, dinv0); }
  k_spmm_ell<64,0,0><<<4096, 256, 0, stream>>>(ell, cnt, Zs, dinv0, ub2, (float*)d_out, nullptr, nullptr);
}